// Round 8
// baseline (651.725 us; speedup 1.0000x reference)
//
#include <hip/hip_runtime.h>
#include <cstdint>

// Problem constants
#define NN     20000      // nodes
#define NE     320000     // input edges
#define ETOT   340000     // edges + self loops
#define K1R    3000       // in_dim
#define K1     3072       // padded K for GEMM1
#define NPAD   20224      // 79*256 padded rows (256-tile GEMM1)
#define NCOL1  2048       // 4 x 512 packed outputs (xl_s|xr_s|xl_p|xr_p)
#define LDA2   1024       // layer-2 A row (hi 512 | lo 512)
#define MU_SZ  1280000    // 20000*64

typedef __bf16 bf16x8 __attribute__((ext_vector_type(8)));
typedef float f32x4 __attribute__((ext_vector_type(4)));
typedef unsigned short u16x8 __attribute__((ext_vector_type(8)));

__device__ inline unsigned short f2bf(float f) {
  union { float f; unsigned u; } v; v.f = f;
  unsigned r = v.u + 0x7FFFu + ((v.u >> 16) & 1u);
  return (unsigned short)(r >> 16);
}
__device__ inline float bf2f(unsigned short h) {
  union { unsigned u; float f; } v; v.u = ((unsigned)h) << 16;
  return v.f;
}

typedef const __attribute__((address_space(1))) void* gas1_t;
typedef __attribute__((address_space(3))) void* las3_t;
__device__ inline void llds16(const void* g, void* l) {
  __builtin_amdgcn_global_load_lds((gas1_t)(uintptr_t)g,
                                   (las3_t)(uint32_t)(uintptr_t)l, 16, 0, 0);
}

// ---------------- conversion / packing ----------------

__global__ __launch_bounds__(256)
void k_convert_x(const float* __restrict__ X, unsigned short* __restrict__ Xb) {
  const int CH = K1 / 8;                       // 384 chunks per row
  int idx = blockIdx.x * 256 + threadIdx.x;
  if (idx >= NPAD * CH) return;
  int r = idx / CH, c8 = (idx % CH) * 8;
  u16x8 o;
  if (r < NN && c8 < K1R) {                    // 3000 % 8 == 0: chunks never straddle
    const float4* p = (const float4*)(X + (size_t)r * K1R + c8);
    float4 a = p[0], b = p[1];
    o[0]=f2bf(a.x); o[1]=f2bf(a.y); o[2]=f2bf(a.z); o[3]=f2bf(a.w);
    o[4]=f2bf(b.x); o[5]=f2bf(b.y); o[6]=f2bf(b.z); o[7]=f2bf(b.w);
  } else {
#pragma unroll
    for (int j = 0; j < 8; j++) o[j] = 0;
  }
  *(u16x8*)(Xb + (size_t)r * K1 + c8) = o;
}

// Pack 4x [3000,512] f32 -> Wp[2048][3072] bf16 (B^T layout), zero-pad k>=3000.
__global__ __launch_bounds__(256)
void k_pack_w1(const float* __restrict__ W0, const float* __restrict__ W1,
               const float* __restrict__ W2, const float* __restrict__ W3,
               unsigned short* __restrict__ Wp) {
  __shared__ float tile[64][65];
  int k0 = blockIdx.x * 64, n0 = blockIdx.y * 64;
  int m = n0 >> 9, c0 = n0 & 511;
  const float* W = (m == 0) ? W0 : (m == 1) ? W1 : (m == 2) ? W2 : W3;
  int tx = threadIdx.x & 63, ty = threadIdx.x >> 6;
#pragma unroll
  for (int rep = 0; rep < 16; rep++) {
    int i = ty + rep * 4;
    int k = k0 + i;
    tile[i][tx] = (k < K1R) ? W[(size_t)k * 512 + c0 + tx] : 0.f;
  }
  __syncthreads();
#pragma unroll
  for (int rep = 0; rep < 16; rep++) {
    int i = ty + rep * 4;
    Wp[(size_t)(n0 + i) * K1 + k0 + tx] = f2bf(tile[tx][i]);
  }
}

// Pack layer-2 weights for BOTH branches: B2[n][k], n<64 Wl, n>=64 Wr; k = kk%512 (hi|lo).
__global__ __launch_bounds__(256)
void k_pack_w2b(const float* __restrict__ Wl_s, const float* __restrict__ Wr_s,
                const float* __restrict__ Wl_p, const float* __restrict__ Wr_p,
                unsigned short* __restrict__ B2s, unsigned short* __restrict__ B2p) {
  int gidx = blockIdx.x * 256 + threadIdx.x;   // grid 1024 -> 262144
  int br = gidx >> 17, idx = gidx & 131071;
  const float* Wl = br ? Wl_p : Wl_s;
  const float* Wr = br ? Wr_p : Wr_s;
  unsigned short* B2 = br ? B2p : B2s;
  int n = idx >> 10, k = idx & 1023, kk = k & 511;
  float v = (n < 64) ? Wl[(size_t)kk * 64 + n] : Wr[(size_t)kk * 64 + (n - 64)];
  B2[idx] = f2bf(v);
}

// ---------------- CSR build ----------------

__global__ __launch_bounds__(256)
void k_count(const int* __restrict__ ei, int* __restrict__ counts) {
  int e = blockIdx.x * 256 + threadIdx.x;
  if (e >= ETOT) return;
  int dst = (e < NE) ? ei[NE + e] : (e - NE);
  atomicAdd(&counts[dst], 1);
}

__global__ void k_scan(const int* __restrict__ counts, int* __restrict__ row_ptr) {
  __shared__ int part[1024];
  int t = threadIdx.x;
  int base = t * 20;
  int loc[20];
  int s = 0;
#pragma unroll
  for (int i = 0; i < 20; i++) {
    int idx = base + i;
    loc[i] = s;
    s += (idx < NN) ? counts[idx] : 0;
  }
  part[t] = s;
  __syncthreads();
  for (int off = 1; off < 1024; off <<= 1) {
    int v = (t >= off) ? part[t - off] : 0;
    __syncthreads();
    part[t] += v;
    __syncthreads();
  }
  int pre = (t > 0) ? part[t - 1] : 0;
#pragma unroll
  for (int i = 0; i < 20; i++) {
    int idx = base + i;
    if (idx <= NN) row_ptr[idx] = pre + loc[i];
  }
}

__global__ __launch_bounds__(256)
void k_scatter(const int* __restrict__ ei, const int* __restrict__ row_ptr,
               int* __restrict__ fill, int* __restrict__ csr_src) {
  int e = blockIdx.x * 256 + threadIdx.x;
  if (e >= ETOT) return;
  int s_, d_;
  if (e < NE) { s_ = ei[e]; d_ = ei[NE + e]; } else { s_ = d_ = e - NE; }
  int pos = row_ptr[d_] + atomicAdd(&fill[d_], 1);
  csr_src[pos] = s_;
}

// ---------------- GEMM1: 256x256, per-wave-half reads (12 b128/wave/tile) ----------------
// C[20224,2048] bf16 = A[20224,3072] * B^T[2048,3072], both bf16, lda=ldb=3072.
// Waves 2M x 4N: wave (wm,wn) owns rows wm*128..+128, cols wn*64..+64, and reads
// ONLY its A-half (wm) and B-half (wn>>1): 8 + 4 ds_read_b128 per tile (A frags
// reused across qn, B frags across qm) — half of R2-R6's traffic.
// Phases = C-quadrants (0,0),(0,1),(1,0),(1,1), 16 MFMA each, dual barriers.
// Staging for t+1: 2 units at P1 (A0',B0') + 2 at P2 (B1',A1'); single vmcnt(0)
// at the tile boundary (~3 phases after issue -> drain cheap). RACE-SAFE: all 4
// units land+publish at the boundary barrier before ANY wave's P1 reads of t+1
// (R7's counted vmcnt(4) left B1'/A1' in flight -> NaN). Overwrite safety: stage
// targets buf^1 whose reads retired before the previous boundary barrier.

#define NT1 48

#define STAGE_ONE do { \
  if (sctr < 4 * NT1) { \
    int ts_ = sctr >> 2, u_ = sctr & 3, sb_ = ts_ & 1; \
    const unsigned short* gb_; char* lb_; int rb_; \
    if (u_ == 0)      { gb_ = A; rb_ = bmBase;       lb_ = lds + (sb_*2+0)*16384; } \
    else if (u_ == 1) { gb_ = B; rb_ = bnBase;       lb_ = lds + 65536 + (sb_*2+0)*16384; } \
    else if (u_ == 2) { gb_ = B; rb_ = bnBase + 128; lb_ = lds + 65536 + (sb_*2+1)*16384; } \
    else              { gb_ = A; rb_ = bmBase + 128; lb_ = lds + (sb_*2+1)*16384; } \
    const unsigned short* g0_ = gb_ + (size_t)(rb_ + trow) * 3072 + ts_ * 64 + scol; \
    llds16(g0_, lb_ + wid * 1024); \
    llds16(g0_ + (size_t)64 * 3072, lb_ + 8192 + wid * 1024); \
    sctr++; \
  } \
} while (0)

#define RDA_Q(QM, DST) do { \
  _Pragma("unroll") \
  for (int rt = 0; rt < 4; rt++) { \
    int r_ = (QM) * 64 + rt * 16 + l15; \
    DST[0][rt] = *(const bf16x8*)(Ah + r_ * 128 + sw0); \
    DST[1][rt] = *(const bf16x8*)(Ah + r_ * 128 + sw1); \
  } \
} while (0)

#define RDB_Q(QN, DST) do { \
  _Pragma("unroll") \
  for (int ct = 0; ct < 2; ct++) { \
    int r_ = bcol0 + (QN) * 32 + ct * 16 + l15; \
    DST[0][ct] = *(const bf16x8*)(Bh + r_ * 128 + sw0); \
    DST[1][ct] = *(const bf16x8*)(Bh + r_ * 128 + sw1); \
  } \
} while (0)

#define MF_Q(QM, QN, AV, BV) do { \
  _Pragma("unroll") \
  for (int rt = 0; rt < 4; rt++) \
    _Pragma("unroll") \
    for (int ct = 0; ct < 2; ct++) { \
      acc[QM][QN][rt][ct] = __builtin_amdgcn_mfma_f32_16x16x32_bf16(AV[0][rt], BV[0][ct], acc[QM][QN][rt][ct], 0, 0, 0); \
      acc[QM][QN][rt][ct] = __builtin_amdgcn_mfma_f32_16x16x32_bf16(AV[1][rt], BV[1][ct], acc[QM][QN][rt][ct], 0, 0, 0); \
    } \
} while (0)

#define PH_SYNC do { \
  asm volatile("" ::: "memory"); \
  __builtin_amdgcn_s_barrier(); \
  asm volatile("s_waitcnt lgkmcnt(0)" ::: "memory"); \
  __builtin_amdgcn_sched_barrier(0); \
  __builtin_amdgcn_s_setprio(1); \
} while (0)

#define PH_END do { \
  __builtin_amdgcn_s_setprio(0); \
  __builtin_amdgcn_sched_barrier(0); \
  __builtin_amdgcn_s_barrier(); \
  asm volatile("" ::: "memory"); \
} while (0)

__global__ __launch_bounds__(512, 2)
void gemm256(const unsigned short* __restrict__ A, const unsigned short* __restrict__ B,
             unsigned short* __restrict__ C) {
  __shared__ char lds[131072];
  int tid = threadIdx.x, wid = tid >> 6, lane = tid & 63;
  int l15 = lane & 15;
  int wm = wid >> 2, wn = wid & 3;               // 2M x 4N waves, 128x64 out each
  int bcol0 = (wn & 1) * 64;                     // col offset within B-half
  int bid = blockIdx.x;
  int bn = bid & 7, bm = bid >> 3;               // bn == XCD
  int bmBase = bm * 256, bnBase = bn * 256;
  int trow = tid >> 3;                           // staging row within 64-row issue
  int scol = ((tid & 7) ^ ((tid >> 3) & 7)) * 8; // pre-swizzled global k-offset (elems)
  int sw0 = (((lane >> 4) + 0) ^ (lane & 7)) * 16;  // read-side swizzled byte col, kk=0
  int sw1 = (((lane >> 4) + 4) ^ (lane & 7)) * 16;  // kk=1
  f32x4 acc[2][2][4][2] = {};                    // [qm][qn][rt][ct]

  int sctr = 0;
  // prologue: stage tile 0 fully, drain, barrier
  for (int i = 0; i < 4; i++) STAGE_ONE;
  asm volatile("s_waitcnt vmcnt(0)" ::: "memory");
  __builtin_amdgcn_s_barrier();
  asm volatile("" ::: "memory");

  for (int t = 0; t < NT1; t++) {
    int buf = t & 1;
    const char* Ah = lds + (buf * 2 + wm) * 16384;
    const char* Bh = lds + 65536 + (buf * 2 + (wn >> 1)) * 16384;
    bf16x8 a[2][4], b0[2][2], b1[2][2];

    // P1: quadrant (0,0); stage A0',B0' of t+1
    RDA_Q(0, a); RDB_Q(0, b0);
    STAGE_ONE; STAGE_ONE;
    PH_SYNC;
    MF_Q(0, 0, a, b0);
    PH_END;

    // P2: quadrant (0,1); stage B1',A1'
    RDB_Q(1, b1);
    STAGE_ONE; STAGE_ONE;
    PH_SYNC;
    MF_Q(0, 1, a, b1);
    PH_END;

    // P3: quadrant (1,0) — reuse b0, overwrite a with qm=1
    RDA_Q(1, a);
    PH_SYNC;
    MF_Q(1, 0, a, b0);
    PH_END;

    // P4: quadrant (1,1) — no reads; boundary drain publishes all 4 staged units
    PH_SYNC;
    MF_Q(1, 1, a, b1);
    __builtin_amdgcn_s_setprio(0);
    __builtin_amdgcn_sched_barrier(0);
    asm volatile("s_waitcnt vmcnt(0)" ::: "memory");
    __builtin_amdgcn_s_barrier();
    asm volatile("" ::: "memory");
  }

  // epilogue: repack each 128x128 quadrant via LDS, store bf16x8 rows
  unsigned short (*sq)[128] = (unsigned short (*)[128])lds;
#pragma unroll
  for (int mh = 0; mh < 2; mh++)
#pragma unroll
    for (int nh = 0; nh < 2; nh++) {
      __syncthreads();
      if (wm == mh && (wn >> 1) == nh) {
#pragma unroll
        for (int qm = 0; qm < 2; qm++)
#pragma unroll
          for (int qn = 0; qn < 2; qn++)
#pragma unroll
            for (int rt = 0; rt < 4; rt++)
#pragma unroll
              for (int ct = 0; ct < 2; ct++)
#pragma unroll
                for (int r = 0; r < 4; r++)
                  sq[qm * 64 + rt * 16 + (lane >> 4) * 4 + r]
                    [(wn & 1) * 64 + qn * 32 + ct * 16 + l15] =
                      f2bf(acc[qm][qn][rt][ct][r]);
      }
      __syncthreads();
#pragma unroll
      for (int it = 0; it < 4; it++) {
        int idx = it * 512 + tid;
        int row = idx >> 4, ch = idx & 15;
        *(u16x8*)(C + (size_t)(bmBase + mh * 128 + row) * NCOL1 + bnBase + nh * 128 + ch * 8) =
            *(const u16x8*)&sq[row][ch * 8];
      }
    }
}

// ---------------- layer-2 GEMM (128-tile m97 structure), both branches in one grid ----------------

__global__ __launch_bounds__(256)
void gemm_l2(const unsigned short* __restrict__ As, const unsigned short* __restrict__ Bs,
             float* __restrict__ Cs,
             const unsigned short* __restrict__ Ap, const unsigned short* __restrict__ Bp,
             float* __restrict__ Cp) {
  const int K = LDA2, lda = LDA2, ldb = LDA2, ldc = 128, mreal = NN;
  const unsigned short* A = blockIdx.y ? Ap : As;
  const unsigned short* B = blockIdx.y ? Bp : Bs;
  float* C = blockIdx.y ? Cp : Cs;
  __shared__ char smem_raw[16384];
  unsigned short* sA = (unsigned short*)smem_raw;
  unsigned short* sB = sA + 128 * 32;
  int bm = blockIdx.x;
  int tid = threadIdx.x, wid = tid >> 6, lane = tid & 63;
  int wr = wid >> 1, wc = wid & 1;
  f32x4 acc[4][4] = {};

  int ar = 32 * wid + (lane >> 2);
  int acol = (lane & 3) * 8;
  const unsigned short* Ag = A + (size_t)(bm * 128 + ar) * lda + acol;
  const unsigned short* Bg = B + (size_t)ar * ldb + acol;
  unsigned short* la0 = sA + (wid * 2) * 512;
  unsigned short* lb0 = sB + (wid * 2) * 512;
  int frow = lane & 15, koff = (lane >> 4) * 8;

  for (int kt = 0; kt < K; kt += 32) {
    llds16(Ag + kt, la0);
    llds16(Ag + kt + (size_t)16 * lda, la0 + 512);
    llds16(Bg + kt, lb0);
    llds16(Bg + kt + (size_t)16 * ldb, lb0 + 512);
    __syncthreads();
    bf16x8 af[4], bfr[4];
#pragma unroll
    for (int mi = 0; mi < 4; mi++)
      af[mi] = *(const bf16x8*)(sA + (wr * 64 + mi * 16 + frow) * 32 + koff);
#pragma unroll
    for (int ni = 0; ni < 4; ni++)
      bfr[ni] = *(const bf16x8*)(sB + (wc * 64 + ni * 16 + frow) * 32 + koff);
#pragma unroll
    for (int mi = 0; mi < 4; mi++)
#pragma unroll
      for (int ni = 0; ni < 4; ni++)
        acc[mi][ni] = __builtin_amdgcn_mfma_f32_16x16x32_bf16(af[mi], bfr[ni], acc[mi][ni], 0, 0, 0);
    __syncthreads();
  }

#pragma unroll
  for (int mi = 0; mi < 4; mi++) {
    int grow0 = bm * 128 + wr * 64 + mi * 16 + (lane >> 4) * 4;
#pragma unroll
    for (int ni = 0; ni < 4; ni++) {
      int gcol = wc * 64 + ni * 16 + (lane & 15);
#pragma unroll
      for (int r = 0; r < 4; r++) {
        int grow = grow0 + r;
        if (grow < mreal) C[(size_t)grow * ldc + gcol] = acc[mi][ni][r];
      }
    }
  }
}

// ---------------- layer-1 fused edge softmax + aggregate + activation + hi/lo split ----------------

__global__ __launch_bounds__(256)
void edge_agg1(const unsigned short* __restrict__ XL1,
               const int* __restrict__ row_ptr, const int* __restrict__ csr_src,
               const float* __restrict__ att_s, const float* __restrict__ att_p,
               const float* __restrict__ b_s, const float* __restrict__ b_p,
               unsigned short* __restrict__ A2s, unsigned short* __restrict__ A2p) {
  int gw = (blockIdx.x * 256 + threadIdx.x) >> 6;
  if (gw >= NN * 2) return;
  int n = gw >> 1, br = gw & 1;
  int lane = threadIdx.x & 63;
  int cb = lane * 8;
  const float* att = br ? att_p : att_s;
  const float* bias = br ? b_p : b_s;
  float xr[8], at[8], agg[8];
  bf16x8 xrv = *(const bf16x8*)(XL1 + (size_t)n * NCOL1 + br * 1024 + 512 + cb);
#pragma unroll
  for (int j = 0; j < 8; j++) { xr[j] = (float)xrv[j]; at[j] = att[cb + j]; agg[j] = 0.f; }
  float M = -1e30f, S = 0.f;
  const size_t srcoff = (size_t)br * 1024 + cb;
  int pe = row_ptr[n + 1];
  for (int p = row_ptr[n]; p < pe; ++p) {
    int src = csr_src[p];
    bf16x8 mv = *(const bf16x8*)(XL1 + (size_t)src * NCOL1 + srcoff);
    float mj[8], part = 0.f;
#pragma unroll
    for (int j = 0; j < 8; j++) {
      mj[j] = (float)mv[j];
      float t = mj[j] + xr[j];
      t = (t > 0.f) ? t : 0.2f * t;
      part = fmaf(at[j], t, part);
    }
#pragma unroll
    for (int w = 1; w < 16; w <<= 1) part += __shfl_xor(part, w);
    float nm = fmaxf(M, part);
    float fac = __expf(M - nm);
    float wgt = __expf(part - nm);
    S = S * fac + wgt;
#pragma unroll
    for (int j = 0; j < 8; j++) agg[j] = agg[j] * fac + wgt * mj[j];
    M = nm;
  }
  float inv = 1.f / S;
  u16x8 hv, lv;
  unsigned short* A2 = br ? A2p : A2s;
#pragma unroll
  for (int j = 0; j < 8; j++) {
    float v = agg[j] * inv + bias[cb + j];
    if (!br) v = fmaxf(v, 0.f);
    unsigned short h = f2bf(v);
    float lo = v - bf2f(h);
    hv[j] = h; lv[j] = f2bf(lo);
  }
  *(u16x8*)(A2 + (size_t)n * LDA2 + cb) = hv;
  *(u16x8*)(A2 + (size_t)n * LDA2 + 512 + cb) = lv;
}

// ---------------- layer-2 fused edge softmax + aggregate + final epilogue ----------------

__global__ __launch_bounds__(256)
void edge_agg2(const float* __restrict__ C2s, const float* __restrict__ C2p,
               const int* __restrict__ row_ptr, const int* __restrict__ csr_src,
               const float* __restrict__ att_s, const float* __restrict__ att_p,
               const float* __restrict__ b_s, const float* __restrict__ b_p,
               float* __restrict__ out) {
  int gw = (blockIdx.x * 256 + threadIdx.x) >> 6;
  if (gw >= NN * 2) return;
  int n = gw >> 1, br = gw & 1;
  int lane = threadIdx.x & 63;
  const float* C2 = br ? C2p : C2s;
  float xr = C2[(size_t)n * 128 + 64 + lane];
  float at = (br ? att_p : att_s)[lane];
  float M = -1e30f, S = 0.f, agg = 0.f;
  int pe = row_ptr[n + 1];
  for (int p = row_ptr[n]; p < pe; ++p) {
    int src = csr_src[p];
    float m = C2[(size_t)src * 128 + lane];
    float t = m + xr;
    t = (t > 0.f) ? t : 0.2f * t;
    float part = at * t;
#pragma unroll
    for (int w = 1; w < 64; w <<= 1) part += __shfl_xor(part, w);
    float nm = fmaxf(M, part);
    float fac = __expf(M - nm);
    float wgt = __expf(part - nm);
    S = S * fac + wgt;
    agg = agg * fac + wgt * m;
    M = nm;
  }
  float v = agg / S + (br ? b_p : b_s)[lane];
  if (lane < 32) {
    out[(size_t)n * 64 + br * 32 + lane] = v;
  } else {
    float sp = fmaxf(v, 0.f) + log1pf(__expf(-fabsf(v))) + 1e-6f;
    out[(size_t)MU_SZ + n * 64 + br * 32 + (lane - 32)] = sp;
  }
}

// ---------------- host ----------------

extern "C" void kernel_launch(void* const* d_in, const int* in_sizes, int n_in,
                              void* d_out, int out_size, void* d_ws, size_t ws_size,
                              hipStream_t stream) {
  const float* x      = (const float*)d_in[0];
  const int*   ei     = (const int*)d_in[1];
  const float* Wl_s1  = (const float*)d_in[2];
  const float* Wr_s1  = (const float*)d_in[3];
  const float* att_s1 = (const float*)d_in[4];
  const float* b_s1   = (const float*)d_in[5];
  const float* Wl_s2  = (const float*)d_in[6];
  const float* Wr_s2  = (const float*)d_in[7];
  const float* att_s2 = (const float*)d_in[8];
  const float* b_s2   = (const float*)d_in[9];
  const float* Wl_p1  = (const float*)d_in[10];
  const float* Wr_p1  = (const float*)d_in[11];
  const float* att_p1 = (const float*)d_in[12];
  const float* b_p1   = (const float*)d_in[13];
  const float* Wl_p2  = (const float*)d_in[14];
  const float* Wr_p2  = (const float*)d_in[15];
  const float* att_p2 = (const float*)d_in[16];
  const float* b_p2   = (const float*)d_in[17];

  char* ws = (char*)d_ws;
  // Region R0 [0, 124.3MB): Xb during GEMM1; reused afterwards for layer-2 buffers.
  unsigned short* Xb   = (unsigned short*)(ws + 0);           // 20224*3072*2 = 124,256,256
  unsigned short* A2s  = (unsigned short*)(ws + 0);           // 41,156,608
  unsigned short* A2p  = (unsigned short*)(ws + 41156608);    // 41,156,608
  float*          C2s  = (float*)(ws + 82313216);             // 10,240,000
  float*          C2p  = (float*)(ws + 92553216);             // 10,240,000
  unsigned short* B2s  = (unsigned short*)(ws + 102793216);   // 262,144
  unsigned short* B2p  = (unsigned short*)(ws + 103055360);   // 262,144
  unsigned short* Wp   = (unsigned short*)(ws + 124256256);   // 12,582,912
  unsigned short* XL1  = (unsigned short*)(ws + 136839168);   // 20224*2048*2 = 82,837,504
  int* counts  = (int*)(ws + 219676672);
  int* fill    = (int*)(ws + 219756672);
  int* row_ptr = (int*)(ws + 219836672);
  int* csr_src = (int*)(ws + 219916688);                      // ends ~221.3 MB

  hipMemsetAsync(counts, 0, NN * sizeof(int), stream);
  hipMemsetAsync(fill, 0, NN * sizeof(int), stream);

  k_convert_x<<<30336, 256, 0, stream>>>(x, Xb);
  k_pack_w1<<<dim3(48, 32), 256, 0, stream>>>(Wl_s1, Wr_s1, Wl_p1, Wr_p1, Wp);
  k_count<<<(ETOT + 255) / 256, 256, 0, stream>>>(ei, counts);
  k_scan<<<1, 1024, 0, stream>>>(counts, row_ptr);
  k_scatter<<<(ETOT + 255) / 256, 256, 0, stream>>>(ei, row_ptr, fill, csr_src);

  // XL1[n, 0:512|512:1024|1024:1536|1536:2048] = x@{Wl_s1|Wr_s1|Wl_p1|Wr_p1}, bf16
  gemm256<<<632, 512, 0, stream>>>(Xb, Wp, XL1);

  k_pack_w2b<<<1024, 256, 0, stream>>>(Wl_s2, Wr_s2, Wl_p2, Wr_p2, B2s, B2p);

  edge_agg1<<<10000, 256, 0, stream>>>(XL1, row_ptr, csr_src, att_s1, att_p1, b_s1, b_p1, A2s, A2p);

  // layer-2: both branches, one launch
  gemm_l2<<<dim3(157, 2), 256, 0, stream>>>(A2s, B2s, C2s, A2p, B2p, C2p);

  edge_agg2<<<10000, 256, 0, stream>>>(C2s, C2p, row_ptr, csr_src, att_s2, att_p2, b_s2, b_p2, (float*)d_out);
}

// Round 9
// 613.483 us; speedup vs baseline: 1.0623x; 1.0623x over previous
//
#include <hip/hip_runtime.h>
#include <cstdint>

// Problem constants
#define NN     20000      // nodes
#define NE     320000     // input edges
#define ETOT   340000     // edges + self loops
#define K1R    3000       // in_dim
#define K1     3072       // padded K for GEMM1
#define NPAD   20224      // 79*256 padded rows (256-tile GEMM1)
#define NCOL1  2048       // 4 x 512 packed outputs (xl_s|xr_s|xl_p|xr_p)
#define LDA2   1024       // layer-2 A row (hi 512 | lo 512)
#define MU_SZ  1280000    // 20000*64

typedef __bf16 bf16x8 __attribute__((ext_vector_type(8)));
typedef float f32x4 __attribute__((ext_vector_type(4)));
typedef unsigned short u16x8 __attribute__((ext_vector_type(8)));

__device__ inline unsigned short f2bf(float f) {
  union { float f; unsigned u; } v; v.f = f;
  unsigned r = v.u + 0x7FFFu + ((v.u >> 16) & 1u);
  return (unsigned short)(r >> 16);
}
__device__ inline float bf2f(unsigned short h) {
  union { unsigned u; float f; } v; v.u = ((unsigned)h) << 16;
  return v.f;
}

typedef const __attribute__((address_space(1))) void* gas1_t;
typedef __attribute__((address_space(3))) void* las3_t;
__device__ inline void llds16(const void* g, void* l) {
  __builtin_amdgcn_global_load_lds((gas1_t)(uintptr_t)g,
                                   (las3_t)(uint32_t)(uintptr_t)l, 16, 0, 0);
}

// ---------------- conversion / packing ----------------

__global__ __launch_bounds__(256)
void k_convert_x(const float* __restrict__ X, unsigned short* __restrict__ Xb) {
  const int CH = K1 / 8;                       // 384 chunks per row
  int idx = blockIdx.x * 256 + threadIdx.x;
  if (idx >= NPAD * CH) return;
  int r = idx / CH, c8 = (idx % CH) * 8;
  u16x8 o;
  if (r < NN && c8 < K1R) {                    // 3000 % 8 == 0: chunks never straddle
    const float4* p = (const float4*)(X + (size_t)r * K1R + c8);
    float4 a = p[0], b = p[1];
    o[0]=f2bf(a.x); o[1]=f2bf(a.y); o[2]=f2bf(a.z); o[3]=f2bf(a.w);
    o[4]=f2bf(b.x); o[5]=f2bf(b.y); o[6]=f2bf(b.z); o[7]=f2bf(b.w);
  } else {
#pragma unroll
    for (int j = 0; j < 8; j++) o[j] = 0;
  }
  *(u16x8*)(Xb + (size_t)r * K1 + c8) = o;
}

// Pack 4x [3000,512] f32 -> Wp[2048][3072] bf16 (B^T layout), zero-pad k>=3000.
__global__ __launch_bounds__(256)
void k_pack_w1(const float* __restrict__ W0, const float* __restrict__ W1,
               const float* __restrict__ W2, const float* __restrict__ W3,
               unsigned short* __restrict__ Wp) {
  __shared__ float tile[64][65];
  int k0 = blockIdx.x * 64, n0 = blockIdx.y * 64;
  int m = n0 >> 9, c0 = n0 & 511;
  const float* W = (m == 0) ? W0 : (m == 1) ? W1 : (m == 2) ? W2 : W3;
  int tx = threadIdx.x & 63, ty = threadIdx.x >> 6;
#pragma unroll
  for (int rep = 0; rep < 16; rep++) {
    int i = ty + rep * 4;
    int k = k0 + i;
    tile[i][tx] = (k < K1R) ? W[(size_t)k * 512 + c0 + tx] : 0.f;
  }
  __syncthreads();
#pragma unroll
  for (int rep = 0; rep < 16; rep++) {
    int i = ty + rep * 4;
    Wp[(size_t)(n0 + i) * K1 + k0 + tx] = f2bf(tile[tx][i]);
  }
}

// Pack layer-2 weights for BOTH branches: B2[n][k], n<64 Wl, n>=64 Wr; k = kk%512 (hi|lo).
__global__ __launch_bounds__(256)
void k_pack_w2b(const float* __restrict__ Wl_s, const float* __restrict__ Wr_s,
                const float* __restrict__ Wl_p, const float* __restrict__ Wr_p,
                unsigned short* __restrict__ B2s, unsigned short* __restrict__ B2p) {
  int gidx = blockIdx.x * 256 + threadIdx.x;   // grid 1024 -> 262144
  int br = gidx >> 17, idx = gidx & 131071;
  const float* Wl = br ? Wl_p : Wl_s;
  const float* Wr = br ? Wr_p : Wr_s;
  unsigned short* B2 = br ? B2p : B2s;
  int n = idx >> 10, k = idx & 1023, kk = k & 511;
  float v = (n < 64) ? Wl[(size_t)kk * 64 + n] : Wr[(size_t)kk * 64 + (n - 64)];
  B2[idx] = f2bf(v);
}

// ---------------- CSR build ----------------

__global__ __launch_bounds__(256)
void k_count(const int* __restrict__ ei, int* __restrict__ counts) {
  int e = blockIdx.x * 256 + threadIdx.x;
  if (e >= ETOT) return;
  int dst = (e < NE) ? ei[NE + e] : (e - NE);
  atomicAdd(&counts[dst], 1);
}

__global__ void k_scan(const int* __restrict__ counts, int* __restrict__ row_ptr) {
  __shared__ int part[1024];
  int t = threadIdx.x;
  int base = t * 20;
  int loc[20];
  int s = 0;
#pragma unroll
  for (int i = 0; i < 20; i++) {
    int idx = base + i;
    loc[i] = s;
    s += (idx < NN) ? counts[idx] : 0;
  }
  part[t] = s;
  __syncthreads();
  for (int off = 1; off < 1024; off <<= 1) {
    int v = (t >= off) ? part[t - off] : 0;
    __syncthreads();
    part[t] += v;
    __syncthreads();
  }
  int pre = (t > 0) ? part[t - 1] : 0;
#pragma unroll
  for (int i = 0; i < 20; i++) {
    int idx = base + i;
    if (idx <= NN) row_ptr[idx] = pre + loc[i];
  }
}

__global__ __launch_bounds__(256)
void k_scatter(const int* __restrict__ ei, const int* __restrict__ row_ptr,
               int* __restrict__ fill, int* __restrict__ csr_src) {
  int e = blockIdx.x * 256 + threadIdx.x;
  if (e >= ETOT) return;
  int s_, d_;
  if (e < NE) { s_ = ei[e]; d_ = ei[NE + e]; } else { s_ = d_ = e - NE; }
  int pos = row_ptr[d_] + atomicAdd(&fill[d_], 1);
  csr_src[pos] = s_;
}

// ---------------- GEMM1: 256x256, role-staggered waves, 1 barrier per K-tile ----------------
// (best measured variant: R6, 298-303 us)

#define NT1 48

#define STAGE_ONE do { \
  if (sctr < 4 * NT1) { \
    int ts_ = sctr >> 2, u_ = sctr & 3, sb_ = ts_ & 1; \
    const unsigned short* gb_; char* lb_; int rb_; \
    if (u_ == 0)      { gb_ = A; rb_ = bmBase + 128; lb_ = lds + (sb_*2+1)*16384; } \
    else if (u_ == 1) { gb_ = B; rb_ = bnBase + 128; lb_ = lds + 65536 + (sb_*2+1)*16384; } \
    else if (u_ == 2) { gb_ = B; rb_ = bnBase;       lb_ = lds + 65536 + (sb_*2+0)*16384; } \
    else              { gb_ = A; rb_ = bmBase;       lb_ = lds + (sb_*2+0)*16384; } \
    const unsigned short* g0_ = gb_ + (size_t)(rb_ + trow) * 3072 + ts_ * 64 + scol; \
    llds16(g0_, lb_ + wid * 1024); \
    llds16(g0_ + (size_t)64 * 3072, lb_ + 8192 + wid * 1024); \
    sctr++; \
  } \
} while (0)

#define RDA(DST, BASE) do { \
  _Pragma("unroll") \
  for (int mi = 0; mi < 2; mi++) { \
    int r_ = rw * 32 + mi * 16 + l15; \
    DST[0][mi] = *(const bf16x8*)((BASE) + r_ * 128 + sw0); \
    DST[1][mi] = *(const bf16x8*)((BASE) + r_ * 128 + sw1); \
  } \
} while (0)

#define RDB(DST, BASE) do { \
  _Pragma("unroll") \
  for (int ni = 0; ni < 4; ni++) { \
    int r_ = cw * 64 + ni * 16 + l15; \
    DST[0][ni] = *(const bf16x8*)((BASE) + r_ * 128 + sw0); \
    DST[1][ni] = *(const bf16x8*)((BASE) + r_ * 128 + sw1); \
  } \
} while (0)

#define MF(MH, NH, AV, BV) do { \
  __builtin_amdgcn_s_setprio(1); \
  _Pragma("unroll") \
  for (int mi = 0; mi < 2; mi++) \
    _Pragma("unroll") \
    for (int ni = 0; ni < 4; ni++) { \
      acc[MH][NH][mi][ni] = __builtin_amdgcn_mfma_f32_16x16x32_bf16(AV[0][mi], BV[0][ni], acc[MH][NH][mi][ni], 0, 0, 0); \
      acc[MH][NH][mi][ni] = __builtin_amdgcn_mfma_f32_16x16x32_bf16(AV[1][mi], BV[1][ni], acc[MH][NH][mi][ni], 0, 0, 0); \
    } \
  __builtin_amdgcn_s_setprio(0); \
} while (0)

__global__ __launch_bounds__(512, 2)
void gemm256(const unsigned short* __restrict__ A, const unsigned short* __restrict__ B,
             unsigned short* __restrict__ C) {
  __shared__ char lds[131072];
  int tid = threadIdx.x, wid = tid >> 6, lane = tid & 63;
  int l15 = lane & 15;
  int rw = wid & 3, cw = wid >> 2;               // 4 row-blocks x 2 col-blocks per quadrant
  int role = (wid >> 2) & 1;                     // SIMD-paired waves get opposite roles
  int bid = blockIdx.x;
  int bn = bid & 7, bm = bid >> 3;               // bn == XCD
  int bmBase = bm * 256, bnBase = bn * 256;
  int trow = tid >> 3;                           // staging row within 64-row issue
  int scol = ((tid & 7) ^ ((tid >> 3) & 7)) * 8; // pre-swizzled global k-offset (elems)
  int sw0 = (((lane >> 4) + 0) ^ (lane & 7)) * 16;  // read-side swizzled byte col, kk=0
  int sw1 = (((lane >> 4) + 4) ^ (lane & 7)) * 16;  // kk=1
  f32x4 acc[2][2][2][4] = {};

  int sctr = 0;
  // prologue: stage tile 0 fully, then wait for it
  for (int i = 0; i < 4; i++) STAGE_ONE;
  asm volatile("s_waitcnt vmcnt(0)" ::: "memory");
  __builtin_amdgcn_s_barrier();
  asm volatile("" ::: "memory");

  for (int t = 0; t < NT1; t++) {
    int buf = t & 1;
    const char* A0h = lds + (buf * 2 + 0) * 16384;
    const char* A1h = lds + (buf * 2 + 1) * 16384;
    const char* B0h = lds + 65536 + (buf * 2 + 0) * 16384;
    const char* B1h = lds + 65536 + (buf * 2 + 1) * 16384;
    bf16x8 a0[2][2], a1[2][2], b0[2][4], b1[2][4];

    if (role == 0) {
      STAGE_ONE;
      RDA(a0, A0h); RDB(b0, B0h);
      MF(0, 0, a0, b0);
      STAGE_ONE;
      RDA(a1, A1h);
      MF(1, 0, a1, b0);
      STAGE_ONE;
      RDB(b1, B1h);
      MF(1, 1, a1, b1);
      STAGE_ONE;
      MF(0, 1, a0, b1);
    } else {
      STAGE_ONE;
      RDA(a1, A1h); RDB(b1, B1h);
      MF(1, 1, a1, b1);
      STAGE_ONE;
      RDA(a0, A0h);
      MF(0, 1, a0, b1);
      STAGE_ONE;
      RDB(b0, B0h);
      MF(0, 0, a0, b0);
      STAGE_ONE;
      MF(1, 0, a1, b0);
    }
    asm volatile("s_waitcnt vmcnt(0)" ::: "memory");
    __builtin_amdgcn_s_barrier();
    asm volatile("" ::: "memory");
  }

  // epilogue: repack each 128x128 quadrant via LDS, store bf16x8 rows
  unsigned short (*sq)[128] = (unsigned short (*)[128])lds;
#pragma unroll
  for (int mh = 0; mh < 2; mh++)
#pragma unroll
    for (int nh = 0; nh < 2; nh++) {
      __syncthreads();
#pragma unroll
      for (int mi = 0; mi < 2; mi++)
#pragma unroll
        for (int ni = 0; ni < 4; ni++)
#pragma unroll
          for (int r = 0; r < 4; r++)
            sq[rw * 32 + mi * 16 + (lane >> 4) * 4 + r][cw * 64 + ni * 16 + l15] =
                f2bf(acc[mh][nh][mi][ni][r]);
      __syncthreads();
#pragma unroll
      for (int it = 0; it < 4; it++) {
        int idx = it * 512 + tid;
        int row = idx >> 4, ch = idx & 15;
        *(u16x8*)(C + (size_t)(bmBase + mh * 128 + row) * NCOL1 + bnBase + nh * 128 + ch * 8) =
            *(const u16x8*)&sq[row][ch * 8];
      }
    }
}

// ---------------- layer-2 GEMM (128-tile m97 structure), both branches in one grid ----------------

__global__ __launch_bounds__(256)
void gemm_l2(const unsigned short* __restrict__ As, const unsigned short* __restrict__ Bs,
             float* __restrict__ Cs,
             const unsigned short* __restrict__ Ap, const unsigned short* __restrict__ Bp,
             float* __restrict__ Cp) {
  const int K = LDA2, lda = LDA2, ldb = LDA2, ldc = 128, mreal = NN;
  const unsigned short* A = blockIdx.y ? Ap : As;
  const unsigned short* B = blockIdx.y ? Bp : Bs;
  float* C = blockIdx.y ? Cp : Cs;
  __shared__ char smem_raw[16384];
  unsigned short* sA = (unsigned short*)smem_raw;
  unsigned short* sB = sA + 128 * 32;
  int bm = blockIdx.x;
  int tid = threadIdx.x, wid = tid >> 6, lane = tid & 63;
  int wr = wid >> 1, wc = wid & 1;
  f32x4 acc[4][4] = {};

  int ar = 32 * wid + (lane >> 2);
  int acol = (lane & 3) * 8;
  const unsigned short* Ag = A + (size_t)(bm * 128 + ar) * lda + acol;
  const unsigned short* Bg = B + (size_t)ar * ldb + acol;
  unsigned short* la0 = sA + (wid * 2) * 512;
  unsigned short* lb0 = sB + (wid * 2) * 512;
  int frow = lane & 15, koff = (lane >> 4) * 8;

  for (int kt = 0; kt < K; kt += 32) {
    llds16(Ag + kt, la0);
    llds16(Ag + kt + (size_t)16 * lda, la0 + 512);
    llds16(Bg + kt, lb0);
    llds16(Bg + kt + (size_t)16 * ldb, lb0 + 512);
    __syncthreads();
    bf16x8 af[4], bfr[4];
#pragma unroll
    for (int mi = 0; mi < 4; mi++)
      af[mi] = *(const bf16x8*)(sA + (wr * 64 + mi * 16 + frow) * 32 + koff);
#pragma unroll
    for (int ni = 0; ni < 4; ni++)
      bfr[ni] = *(const bf16x8*)(sB + (wc * 64 + ni * 16 + frow) * 32 + koff);
#pragma unroll
    for (int mi = 0; mi < 4; mi++)
#pragma unroll
      for (int ni = 0; ni < 4; ni++)
        acc[mi][ni] = __builtin_amdgcn_mfma_f32_16x16x32_bf16(af[mi], bfr[ni], acc[mi][ni], 0, 0, 0);
    __syncthreads();
  }

#pragma unroll
  for (int mi = 0; mi < 4; mi++) {
    int grow0 = bm * 128 + wr * 64 + mi * 16 + (lane >> 4) * 4;
#pragma unroll
    for (int ni = 0; ni < 4; ni++) {
      int gcol = wc * 64 + ni * 16 + (lane & 15);
#pragma unroll
      for (int r = 0; r < 4; r++) {
        int grow = grow0 + r;
        if (grow < mreal) C[(size_t)grow * ldc + gcol] = acc[mi][ni][r];
      }
    }
  }
}

// ---------------- layer-1 edge softmax+aggregate: BOTH branches per wave + prefetch -------
// one wave per node; lane covers 8 channels of each branch's 512.

__global__ __launch_bounds__(256)
void edge_agg1(const unsigned short* __restrict__ XL1,
               const int* __restrict__ row_ptr, const int* __restrict__ csr_src,
               const float* __restrict__ att_s, const float* __restrict__ att_p,
               const float* __restrict__ b_s, const float* __restrict__ b_p,
               unsigned short* __restrict__ A2s, unsigned short* __restrict__ A2p) {
  int n = (blockIdx.x * 256 + threadIdx.x) >> 6;
  if (n >= NN) return;
  int lane = threadIdx.x & 63;
  int cb = lane * 8;
  float xs[8], xp[8], as_[8], ap_[8], aggs[8], aggp[8];
  {
    bf16x8 xsv = *(const bf16x8*)(XL1 + (size_t)n * NCOL1 + 512 + cb);
    bf16x8 xpv = *(const bf16x8*)(XL1 + (size_t)n * NCOL1 + 1536 + cb);
    float4 a0 = *(const float4*)(att_s + cb), a1 = *(const float4*)(att_s + cb + 4);
    float4 a2 = *(const float4*)(att_p + cb), a3 = *(const float4*)(att_p + cb + 4);
    as_[0]=a0.x; as_[1]=a0.y; as_[2]=a0.z; as_[3]=a0.w; as_[4]=a1.x; as_[5]=a1.y; as_[6]=a1.z; as_[7]=a1.w;
    ap_[0]=a2.x; ap_[1]=a2.y; ap_[2]=a2.z; ap_[3]=a2.w; ap_[4]=a3.x; ap_[5]=a3.y; ap_[6]=a3.z; ap_[7]=a3.w;
#pragma unroll
    for (int j = 0; j < 8; j++) { xs[j] = (float)xsv[j]; xp[j] = (float)xpv[j]; aggs[j] = 0.f; aggp[j] = 0.f; }
  }
  float Ms = -1e30f, Ss = 0.f, Mp = -1e30f, Sp = 0.f;
  int p0 = row_ptr[n], pe = row_ptr[n + 1];
  // prefetch edge p0
  int src = csr_src[p0];
  bf16x8 ms = *(const bf16x8*)(XL1 + (size_t)src * NCOL1 + cb);
  bf16x8 mp = *(const bf16x8*)(XL1 + (size_t)src * NCOL1 + 1024 + cb);
  for (int p = p0; p < pe; ++p) {
    bf16x8 cs = ms, cp = mp;
    if (p + 1 < pe) {                             // wave-uniform branch
      int s2 = csr_src[p + 1];
      ms = *(const bf16x8*)(XL1 + (size_t)s2 * NCOL1 + cb);
      mp = *(const bf16x8*)(XL1 + (size_t)s2 * NCOL1 + 1024 + cb);
    }
    float mjs[8], mjp[8], ps_ = 0.f, pp_ = 0.f;
#pragma unroll
    for (int j = 0; j < 8; j++) {
      mjs[j] = (float)cs[j];
      float t = mjs[j] + xs[j];
      t = (t > 0.f) ? t : 0.2f * t;
      ps_ = fmaf(as_[j], t, ps_);
      mjp[j] = (float)cp[j];
      float u = mjp[j] + xp[j];
      u = (u > 0.f) ? u : 0.2f * u;
      pp_ = fmaf(ap_[j], u, pp_);
    }
#pragma unroll
    for (int w = 1; w < 16; w <<= 1) { ps_ += __shfl_xor(ps_, w); pp_ += __shfl_xor(pp_, w); }
    float nms = fmaxf(Ms, ps_);
    float fs = __expf(Ms - nms), ws_ = __expf(ps_ - nms);
    Ss = Ss * fs + ws_;
    float nmp = fmaxf(Mp, pp_);
    float fp = __expf(Mp - nmp), wp_ = __expf(pp_ - nmp);
    Sp = Sp * fp + wp_;
#pragma unroll
    for (int j = 0; j < 8; j++) {
      aggs[j] = aggs[j] * fs + ws_ * mjs[j];
      aggp[j] = aggp[j] * fp + wp_ * mjp[j];
    }
    Ms = nms; Mp = nmp;
  }
  float invs = 1.f / Ss, invp = 1.f / Sp;
  u16x8 hs, ls, hp, lp;
#pragma unroll
  for (int j = 0; j < 8; j++) {
    float v = fmaxf(aggs[j] * invs + b_s[cb + j], 0.f);   // relu on s-branch
    unsigned short h = f2bf(v);
    hs[j] = h; ls[j] = f2bf(v - bf2f(h));
    float u = aggp[j] * invp + b_p[cb + j];
    unsigned short h2 = f2bf(u);
    hp[j] = h2; lp[j] = f2bf(u - bf2f(h2));
  }
  *(u16x8*)(A2s + (size_t)n * LDA2 + cb) = hs;
  *(u16x8*)(A2s + (size_t)n * LDA2 + 512 + cb) = ls;
  *(u16x8*)(A2p + (size_t)n * LDA2 + cb) = hp;
  *(u16x8*)(A2p + (size_t)n * LDA2 + 512 + cb) = lp;
}

// ---------------- layer-2 edge softmax+aggregate+epilogue: BOTH branches per wave + prefetch ----

__global__ __launch_bounds__(256)
void edge_agg2(const float* __restrict__ C2s, const float* __restrict__ C2p,
               const int* __restrict__ row_ptr, const int* __restrict__ csr_src,
               const float* __restrict__ att_s, const float* __restrict__ att_p,
               const float* __restrict__ b_s, const float* __restrict__ b_p,
               float* __restrict__ out) {
  int n = (blockIdx.x * 256 + threadIdx.x) >> 6;
  if (n >= NN) return;
  int lane = threadIdx.x & 63;
  float xrs = C2s[(size_t)n * 128 + 64 + lane];
  float xrp = C2p[(size_t)n * 128 + 64 + lane];
  float ats = att_s[lane], atp = att_p[lane];
  float Ms = -1e30f, Ss = 0.f, ags = 0.f;
  float Mp = -1e30f, Sp = 0.f, agp = 0.f;
  int p0 = row_ptr[n], pe = row_ptr[n + 1];
  int src = csr_src[p0];
  float ms = C2s[(size_t)src * 128 + lane];
  float mp = C2p[(size_t)src * 128 + lane];
  for (int p = p0; p < pe; ++p) {
    float cs = ms, cp = mp;
    if (p + 1 < pe) {
      int s2 = csr_src[p + 1];
      ms = C2s[(size_t)s2 * 128 + lane];
      mp = C2p[(size_t)s2 * 128 + lane];
    }
    float t = cs + xrs; t = (t > 0.f) ? t : 0.2f * t;
    float u = cp + xrp; u = (u > 0.f) ? u : 0.2f * u;
    float ps_ = ats * t, pp_ = atp * u;
#pragma unroll
    for (int w = 1; w < 64; w <<= 1) { ps_ += __shfl_xor(ps_, w); pp_ += __shfl_xor(pp_, w); }
    float nms = fmaxf(Ms, ps_);
    float fs = __expf(Ms - nms), ws_ = __expf(ps_ - nms);
    Ss = Ss * fs + ws_; ags = ags * fs + ws_ * cs; Ms = nms;
    float nmp = fmaxf(Mp, pp_);
    float fp = __expf(Mp - nmp), wp_ = __expf(pp_ - nmp);
    Sp = Sp * fp + wp_; agp = agp * fp + wp_ * cp; Mp = nmp;
  }
  float vs = ags / Ss + b_s[lane];
  float vp = agp / Sp + b_p[lane];
  if (lane < 32) {
    out[(size_t)n * 64 + lane] = vs;                                 // mu_s
    out[(size_t)n * 64 + 32 + lane] = vp;                            // mu_p
  } else {
    float sps = fmaxf(vs, 0.f) + log1pf(__expf(-fabsf(vs))) + 1e-6f;
    float spp = fmaxf(vp, 0.f) + log1pf(__expf(-fabsf(vp))) + 1e-6f;
    out[(size_t)MU_SZ + n * 64 + (lane - 32)] = sps;                 // sig_s
    out[(size_t)MU_SZ + n * 64 + 32 + (lane - 32)] = spp;            // sig_p
  }
}

// ---------------- host ----------------

extern "C" void kernel_launch(void* const* d_in, const int* in_sizes, int n_in,
                              void* d_out, int out_size, void* d_ws, size_t ws_size,
                              hipStream_t stream) {
  const float* x      = (const float*)d_in[0];
  const int*   ei     = (const int*)d_in[1];
  const float* Wl_s1  = (const float*)d_in[2];
  const float* Wr_s1  = (const float*)d_in[3];
  const float* att_s1 = (const float*)d_in[4];
  const float* b_s1   = (const float*)d_in[5];
  const float* Wl_s2  = (const float*)d_in[6];
  const float* Wr_s2  = (const float*)d_in[7];
  const float* att_s2 = (const float*)d_in[8];
  const float* b_s2   = (const float*)d_in[9];
  const float* Wl_p1  = (const float*)d_in[10];
  const float* Wr_p1  = (const float*)d_in[11];
  const float* att_p1 = (const float*)d_in[12];
  const float* b_p1   = (const float*)d_in[13];
  const float* Wl_p2  = (const float*)d_in[14];
  const float* Wr_p2  = (const float*)d_in[15];
  const float* att_p2 = (const float*)d_in[16];
  const float* b_p2   = (const float*)d_in[17];

  char* ws = (char*)d_ws;
  // Region R0 [0, 124.3MB): Xb during GEMM1; reused afterwards for layer-2 buffers.
  unsigned short* Xb   = (unsigned short*)(ws + 0);           // 20224*3072*2 = 124,256,256
  unsigned short* A2s  = (unsigned short*)(ws + 0);           // 41,156,608
  unsigned short* A2p  = (unsigned short*)(ws + 41156608);    // 41,156,608
  float*          C2s  = (float*)(ws + 82313216);             // 10,240,000
  float*          C2p  = (float*)(ws + 92553216);             // 10,240,000
  unsigned short* B2s  = (unsigned short*)(ws + 102793216);   // 262,144
  unsigned short* B2p  = (unsigned short*)(ws + 103055360);   // 262,144
  unsigned short* Wp   = (unsigned short*)(ws + 124256256);   // 12,582,912
  unsigned short* XL1  = (unsigned short*)(ws + 136839168);   // 20224*2048*2 = 82,837,504
  int* counts  = (int*)(ws + 219676672);
  int* fill    = (int*)(ws + 219756672);
  int* row_ptr = (int*)(ws + 219836672);
  int* csr_src = (int*)(ws + 219916688);                      // ends ~221.3 MB

  hipMemsetAsync(counts, 0, NN * sizeof(int), stream);
  hipMemsetAsync(fill, 0, NN * sizeof(int), stream);

  k_convert_x<<<30336, 256, 0, stream>>>(x, Xb);
  k_pack_w1<<<dim3(48, 32), 256, 0, stream>>>(Wl_s1, Wr_s1, Wl_p1, Wr_p1, Wp);
  k_count<<<(ETOT + 255) / 256, 256, 0, stream>>>(ei, counts);
  k_scan<<<1, 1024, 0, stream>>>(counts, row_ptr);
  k_scatter<<<(ETOT + 255) / 256, 256, 0, stream>>>(ei, row_ptr, fill, csr_src);

  // XL1[n, 0:512|512:1024|1024:1536|1536:2048] = x@{Wl_s1|Wr_s1|Wl_p1|Wr_p1}, bf16
  gemm256<<<632, 512, 0, stream>>>(Xb, Wp, XL1);

  k_pack_w2b<<<1024, 256, 0, stream>>>(Wl_s2, Wr_s2, Wl_p2, Wr_p2, B2s, B2p);

  edge_agg1<<<5000, 256, 0, stream>>>(XL1, row_ptr, csr_src, att_s1, att_p1, b_s1, b_p1, A2s, A2p);

  // layer-2: both branches, one launch
  gemm_l2<<<dim3(157, 2), 256, 0, stream>>>(A2s, B2s, C2s, A2p, B2p, C2p);

  edge_agg2<<<5000, 256, 0, stream>>>(C2s, C2p, row_ptr, csr_src, att_s2, att_p2, b_s2, b_p2, (float*)d_out);
}

// Round 10
// 602.832 us; speedup vs baseline: 1.0811x; 1.0177x over previous
//
#include <hip/hip_runtime.h>
#include <cstdint>

// Problem constants
#define NN     20000      // nodes
#define NE     320000     // input edges
#define ETOT   340000     // edges + self loops
#define K1R    3000       // in_dim
#define K1     3072       // padded K for GEMM1
#define NPAD   20224      // 79*256 padded rows (256-tile GEMM1)
#define NCOL1  2048       // 4 x 512 packed outputs (xl_s|xr_s|xl_p|xr_p)
#define LDA2   512        // layer-2 A row (plain bf16, no hi/lo split)
#define MU_SZ  1280000    // 20000*64

typedef __bf16 bf16x8 __attribute__((ext_vector_type(8)));
typedef float f32x4 __attribute__((ext_vector_type(4)));
typedef unsigned short u16x8 __attribute__((ext_vector_type(8)));

__device__ inline unsigned short f2bf(float f) {
  union { float f; unsigned u; } v; v.f = f;
  unsigned r = v.u + 0x7FFFu + ((v.u >> 16) & 1u);
  return (unsigned short)(r >> 16);
}
__device__ inline float bf2f(unsigned short h) {
  union { unsigned u; float f; } v; v.u = ((unsigned)h) << 16;
  return v.f;
}

typedef const __attribute__((address_space(1))) void* gas1_t;
typedef __attribute__((address_space(3))) void* las3_t;
__device__ inline void llds16(const void* g, void* l) {
  __builtin_amdgcn_global_load_lds((gas1_t)(uintptr_t)g,
                                   (las3_t)(uint32_t)(uintptr_t)l, 16, 0, 0);
}

// ---------------- conversion / packing ----------------

__global__ __launch_bounds__(256)
void k_convert_x(const float* __restrict__ X, unsigned short* __restrict__ Xb) {
  const int CH = K1 / 8;                       // 384 chunks per row
  int idx = blockIdx.x * 256 + threadIdx.x;
  if (idx >= NPAD * CH) return;
  int r = idx / CH, c8 = (idx % CH) * 8;
  u16x8 o;
  if (r < NN && c8 < K1R) {                    // 3000 % 8 == 0: chunks never straddle
    const float4* p = (const float4*)(X + (size_t)r * K1R + c8);
    float4 a = p[0], b = p[1];
    o[0]=f2bf(a.x); o[1]=f2bf(a.y); o[2]=f2bf(a.z); o[3]=f2bf(a.w);
    o[4]=f2bf(b.x); o[5]=f2bf(b.y); o[6]=f2bf(b.z); o[7]=f2bf(b.w);
  } else {
#pragma unroll
    for (int j = 0; j < 8; j++) o[j] = 0;
  }
  *(u16x8*)(Xb + (size_t)r * K1 + c8) = o;
}

// Pack 4x [3000,512] f32 -> Wp[2048][3072] bf16 (B^T layout), zero-pad k>=3000.
__global__ __launch_bounds__(256)
void k_pack_w1(const float* __restrict__ W0, const float* __restrict__ W1,
               const float* __restrict__ W2, const float* __restrict__ W3,
               unsigned short* __restrict__ Wp) {
  __shared__ float tile[64][65];
  int k0 = blockIdx.x * 64, n0 = blockIdx.y * 64;
  int m = n0 >> 9, c0 = n0 & 511;
  const float* W = (m == 0) ? W0 : (m == 1) ? W1 : (m == 2) ? W2 : W3;
  int tx = threadIdx.x & 63, ty = threadIdx.x >> 6;
#pragma unroll
  for (int rep = 0; rep < 16; rep++) {
    int i = ty + rep * 4;
    int k = k0 + i;
    tile[i][tx] = (k < K1R) ? W[(size_t)k * 512 + c0 + tx] : 0.f;
  }
  __syncthreads();
#pragma unroll
  for (int rep = 0; rep < 16; rep++) {
    int i = ty + rep * 4;
    Wp[(size_t)(n0 + i) * K1 + k0 + tx] = f2bf(tile[tx][i]);
  }
}

// Pack layer-2 weights for BOTH branches: B2[n][k], k in [0,512); n<64 Wl, n>=64 Wr.
__global__ __launch_bounds__(256)
void k_pack_w2b(const float* __restrict__ Wl_s, const float* __restrict__ Wr_s,
                const float* __restrict__ Wl_p, const float* __restrict__ Wr_p,
                unsigned short* __restrict__ B2s, unsigned short* __restrict__ B2p) {
  int gidx = blockIdx.x * 256 + threadIdx.x;   // grid 512 -> 131072
  int br = gidx >> 16, idx = gidx & 65535;
  const float* Wl = br ? Wl_p : Wl_s;
  const float* Wr = br ? Wr_p : Wr_s;
  unsigned short* B2 = br ? B2p : B2s;
  int n = idx >> 9, k = idx & 511;
  float v = (n < 64) ? Wl[(size_t)k * 64 + n] : Wr[(size_t)k * 64 + (n - 64)];
  B2[idx] = f2bf(v);
}

// ---------------- CSR build ----------------

__global__ __launch_bounds__(256)
void k_count(const int* __restrict__ ei, int* __restrict__ counts) {
  int e = blockIdx.x * 256 + threadIdx.x;
  if (e >= ETOT) return;
  int dst = (e < NE) ? ei[NE + e] : (e - NE);
  atomicAdd(&counts[dst], 1);
}

__global__ void k_scan(const int* __restrict__ counts, int* __restrict__ row_ptr) {
  __shared__ int part[1024];
  int t = threadIdx.x;
  int base = t * 20;
  int loc[20];
  int s = 0;
#pragma unroll
  for (int i = 0; i < 20; i++) {
    int idx = base + i;
    loc[i] = s;
    s += (idx < NN) ? counts[idx] : 0;
  }
  part[t] = s;
  __syncthreads();
  for (int off = 1; off < 1024; off <<= 1) {
    int v = (t >= off) ? part[t - off] : 0;
    __syncthreads();
    part[t] += v;
    __syncthreads();
  }
  int pre = (t > 0) ? part[t - 1] : 0;
#pragma unroll
  for (int i = 0; i < 20; i++) {
    int idx = base + i;
    if (idx <= NN) row_ptr[idx] = pre + loc[i];
  }
}

__global__ __launch_bounds__(256)
void k_scatter(const int* __restrict__ ei, const int* __restrict__ row_ptr,
               int* __restrict__ fill, int* __restrict__ csr_src) {
  int e = blockIdx.x * 256 + threadIdx.x;
  if (e >= ETOT) return;
  int s_, d_;
  if (e < NE) { s_ = ei[e]; d_ = ei[NE + e]; } else { s_ = d_ = e - NE; }
  int pos = row_ptr[d_] + atomicAdd(&fill[d_], 1);
  csr_src[pos] = s_;
}

// ---------------- GEMM1: 256x256, role-staggered waves, 1 barrier per K-tile ----------------
// (best measured variant: R6, 298-303 us)

#define NT1 48

#define STAGE_ONE do { \
  if (sctr < 4 * NT1) { \
    int ts_ = sctr >> 2, u_ = sctr & 3, sb_ = ts_ & 1; \
    const unsigned short* gb_; char* lb_; int rb_; \
    if (u_ == 0)      { gb_ = A; rb_ = bmBase + 128; lb_ = lds + (sb_*2+1)*16384; } \
    else if (u_ == 1) { gb_ = B; rb_ = bnBase + 128; lb_ = lds + 65536 + (sb_*2+1)*16384; } \
    else if (u_ == 2) { gb_ = B; rb_ = bnBase;       lb_ = lds + 65536 + (sb_*2+0)*16384; } \
    else              { gb_ = A; rb_ = bmBase;       lb_ = lds + (sb_*2+0)*16384; } \
    const unsigned short* g0_ = gb_ + (size_t)(rb_ + trow) * 3072 + ts_ * 64 + scol; \
    llds16(g0_, lb_ + wid * 1024); \
    llds16(g0_ + (size_t)64 * 3072, lb_ + 8192 + wid * 1024); \
    sctr++; \
  } \
} while (0)

#define RDA(DST, BASE) do { \
  _Pragma("unroll") \
  for (int mi = 0; mi < 2; mi++) { \
    int r_ = rw * 32 + mi * 16 + l15; \
    DST[0][mi] = *(const bf16x8*)((BASE) + r_ * 128 + sw0); \
    DST[1][mi] = *(const bf16x8*)((BASE) + r_ * 128 + sw1); \
  } \
} while (0)

#define RDB(DST, BASE) do { \
  _Pragma("unroll") \
  for (int ni = 0; ni < 4; ni++) { \
    int r_ = cw * 64 + ni * 16 + l15; \
    DST[0][ni] = *(const bf16x8*)((BASE) + r_ * 128 + sw0); \
    DST[1][ni] = *(const bf16x8*)((BASE) + r_ * 128 + sw1); \
  } \
} while (0)

#define MF(MH, NH, AV, BV) do { \
  __builtin_amdgcn_s_setprio(1); \
  _Pragma("unroll") \
  for (int mi = 0; mi < 2; mi++) \
    _Pragma("unroll") \
    for (int ni = 0; ni < 4; ni++) { \
      acc[MH][NH][mi][ni] = __builtin_amdgcn_mfma_f32_16x16x32_bf16(AV[0][mi], BV[0][ni], acc[MH][NH][mi][ni], 0, 0, 0); \
      acc[MH][NH][mi][ni] = __builtin_amdgcn_mfma_f32_16x16x32_bf16(AV[1][mi], BV[1][ni], acc[MH][NH][mi][ni], 0, 0, 0); \
    } \
  __builtin_amdgcn_s_setprio(0); \
} while (0)

__global__ __launch_bounds__(512, 2)
void gemm256(const unsigned short* __restrict__ A, const unsigned short* __restrict__ B,
             unsigned short* __restrict__ C) {
  __shared__ char lds[131072];
  int tid = threadIdx.x, wid = tid >> 6, lane = tid & 63;
  int l15 = lane & 15;
  int rw = wid & 3, cw = wid >> 2;               // 4 row-blocks x 2 col-blocks per quadrant
  int role = (wid >> 2) & 1;                     // SIMD-paired waves get opposite roles
  int bid = blockIdx.x;
  int bn = bid & 7, bm = bid >> 3;               // bn == XCD
  int bmBase = bm * 256, bnBase = bn * 256;
  int trow = tid >> 3;                           // staging row within 64-row issue
  int scol = ((tid & 7) ^ ((tid >> 3) & 7)) * 8; // pre-swizzled global k-offset (elems)
  int sw0 = (((lane >> 4) + 0) ^ (lane & 7)) * 16;  // read-side swizzled byte col, kk=0
  int sw1 = (((lane >> 4) + 4) ^ (lane & 7)) * 16;  // kk=1
  f32x4 acc[2][2][2][4] = {};

  int sctr = 0;
  // prologue: stage tile 0 fully, then wait for it
  for (int i = 0; i < 4; i++) STAGE_ONE;
  asm volatile("s_waitcnt vmcnt(0)" ::: "memory");
  __builtin_amdgcn_s_barrier();
  asm volatile("" ::: "memory");

  for (int t = 0; t < NT1; t++) {
    int buf = t & 1;
    const char* A0h = lds + (buf * 2 + 0) * 16384;
    const char* A1h = lds + (buf * 2 + 1) * 16384;
    const char* B0h = lds + 65536 + (buf * 2 + 0) * 16384;
    const char* B1h = lds + 65536 + (buf * 2 + 1) * 16384;
    bf16x8 a0[2][2], a1[2][2], b0[2][4], b1[2][4];

    if (role == 0) {
      STAGE_ONE;
      RDA(a0, A0h); RDB(b0, B0h);
      MF(0, 0, a0, b0);
      STAGE_ONE;
      RDA(a1, A1h);
      MF(1, 0, a1, b0);
      STAGE_ONE;
      RDB(b1, B1h);
      MF(1, 1, a1, b1);
      STAGE_ONE;
      MF(0, 1, a0, b1);
    } else {
      STAGE_ONE;
      RDA(a1, A1h); RDB(b1, B1h);
      MF(1, 1, a1, b1);
      STAGE_ONE;
      RDA(a0, A0h);
      MF(0, 1, a0, b1);
      STAGE_ONE;
      RDB(b0, B0h);
      MF(0, 0, a0, b0);
      STAGE_ONE;
      MF(1, 0, a1, b0);
    }
    asm volatile("s_waitcnt vmcnt(0)" ::: "memory");
    __builtin_amdgcn_s_barrier();
    asm volatile("" ::: "memory");
  }

  // epilogue: repack each 128x128 quadrant via LDS, store bf16x8 rows
  unsigned short (*sq)[128] = (unsigned short (*)[128])lds;
#pragma unroll
  for (int mh = 0; mh < 2; mh++)
#pragma unroll
    for (int nh = 0; nh < 2; nh++) {
      __syncthreads();
#pragma unroll
      for (int mi = 0; mi < 2; mi++)
#pragma unroll
        for (int ni = 0; ni < 4; ni++)
#pragma unroll
          for (int r = 0; r < 4; r++)
            sq[rw * 32 + mi * 16 + (lane >> 4) * 4 + r][cw * 64 + ni * 16 + l15] =
                f2bf(acc[mh][nh][mi][ni][r]);
      __syncthreads();
#pragma unroll
      for (int it = 0; it < 4; it++) {
        int idx = it * 512 + tid;
        int row = idx >> 4, ch = idx & 15;
        *(u16x8*)(C + (size_t)(bmBase + mh * 128 + row) * NCOL1 + bnBase + nh * 128 + ch * 8) =
            *(const u16x8*)&sq[row][ch * 8];
      }
    }
}

// ---------------- layer-2 GEMM (128-tile m97 structure), both branches, K=512 ----------------

__global__ __launch_bounds__(256)
void gemm_l2(const unsigned short* __restrict__ As, const unsigned short* __restrict__ Bs,
             float* __restrict__ Cs,
             const unsigned short* __restrict__ Ap, const unsigned short* __restrict__ Bp,
             float* __restrict__ Cp) {
  const int K = LDA2, lda = LDA2, ldb = LDA2, ldc = 128, mreal = NN;
  const unsigned short* A = blockIdx.y ? Ap : As;
  const unsigned short* B = blockIdx.y ? Bp : Bs;
  float* C = blockIdx.y ? Cp : Cs;
  __shared__ char smem_raw[16384];
  unsigned short* sA = (unsigned short*)smem_raw;
  unsigned short* sB = sA + 128 * 32;
  int bm = blockIdx.x;
  int tid = threadIdx.x, wid = tid >> 6, lane = tid & 63;
  int wr = wid >> 1, wc = wid & 1;
  f32x4 acc[4][4] = {};

  int ar = 32 * wid + (lane >> 2);
  int acol = (lane & 3) * 8;
  const unsigned short* Ag = A + (size_t)(bm * 128 + ar) * lda + acol;
  const unsigned short* Bg = B + (size_t)ar * ldb + acol;
  unsigned short* la0 = sA + (wid * 2) * 512;
  unsigned short* lb0 = sB + (wid * 2) * 512;
  int frow = lane & 15, koff = (lane >> 4) * 8;

  for (int kt = 0; kt < K; kt += 32) {
    llds16(Ag + kt, la0);
    llds16(Ag + kt + (size_t)16 * lda, la0 + 512);
    llds16(Bg + kt, lb0);
    llds16(Bg + kt + (size_t)16 * ldb, lb0 + 512);
    __syncthreads();
    bf16x8 af[4], bfr[4];
#pragma unroll
    for (int mi = 0; mi < 4; mi++)
      af[mi] = *(const bf16x8*)(sA + (wr * 64 + mi * 16 + frow) * 32 + koff);
#pragma unroll
    for (int ni = 0; ni < 4; ni++)
      bfr[ni] = *(const bf16x8*)(sB + (wc * 64 + ni * 16 + frow) * 32 + koff);
#pragma unroll
    for (int mi = 0; mi < 4; mi++)
#pragma unroll
      for (int ni = 0; ni < 4; ni++)
        acc[mi][ni] = __builtin_amdgcn_mfma_f32_16x16x32_bf16(af[mi], bfr[ni], acc[mi][ni], 0, 0, 0);
    __syncthreads();
  }

#pragma unroll
  for (int mi = 0; mi < 4; mi++) {
    int grow0 = bm * 128 + wr * 64 + mi * 16 + (lane >> 4) * 4;
#pragma unroll
    for (int ni = 0; ni < 4; ni++) {
      int gcol = wc * 64 + ni * 16 + (lane & 15);
#pragma unroll
      for (int r = 0; r < 4; r++) {
        int grow = grow0 + r;
        if (grow < mreal) C[(size_t)grow * ldc + gcol] = acc[mi][ni][r];
      }
    }
  }
}

// ---------------- layer-1 edge softmax+aggregate: BOTH branches per wave + prefetch -------
// one wave per node; lane covers 8 channels of each branch's 512.

__global__ __launch_bounds__(256)
void edge_agg1(const unsigned short* __restrict__ XL1,
               const int* __restrict__ row_ptr, const int* __restrict__ csr_src,
               const float* __restrict__ att_s, const float* __restrict__ att_p,
               const float* __restrict__ b_s, const float* __restrict__ b_p,
               unsigned short* __restrict__ A2s, unsigned short* __restrict__ A2p) {
  int n = (blockIdx.x * 256 + threadIdx.x) >> 6;
  if (n >= NN) return;
  int lane = threadIdx.x & 63;
  int cb = lane * 8;
  float xs[8], xp[8], as_[8], ap_[8], aggs[8], aggp[8];
  {
    bf16x8 xsv = *(const bf16x8*)(XL1 + (size_t)n * NCOL1 + 512 + cb);
    bf16x8 xpv = *(const bf16x8*)(XL1 + (size_t)n * NCOL1 + 1536 + cb);
    float4 a0 = *(const float4*)(att_s + cb), a1 = *(const float4*)(att_s + cb + 4);
    float4 a2 = *(const float4*)(att_p + cb), a3 = *(const float4*)(att_p + cb + 4);
    as_[0]=a0.x; as_[1]=a0.y; as_[2]=a0.z; as_[3]=a0.w; as_[4]=a1.x; as_[5]=a1.y; as_[6]=a1.z; as_[7]=a1.w;
    ap_[0]=a2.x; ap_[1]=a2.y; ap_[2]=a2.z; ap_[3]=a2.w; ap_[4]=a3.x; ap_[5]=a3.y; ap_[6]=a3.z; ap_[7]=a3.w;
#pragma unroll
    for (int j = 0; j < 8; j++) { xs[j] = (float)xsv[j]; xp[j] = (float)xpv[j]; aggs[j] = 0.f; aggp[j] = 0.f; }
  }
  float Ms = -1e30f, Ss = 0.f, Mp = -1e30f, Sp = 0.f;
  int p0 = row_ptr[n], pe = row_ptr[n + 1];
  // prefetch edge p0
  int src = csr_src[p0];
  bf16x8 ms = *(const bf16x8*)(XL1 + (size_t)src * NCOL1 + cb);
  bf16x8 mp = *(const bf16x8*)(XL1 + (size_t)src * NCOL1 + 1024 + cb);
  for (int p = p0; p < pe; ++p) {
    bf16x8 cs = ms, cp = mp;
    if (p + 1 < pe) {                             // wave-uniform branch
      int s2 = csr_src[p + 1];
      ms = *(const bf16x8*)(XL1 + (size_t)s2 * NCOL1 + cb);
      mp = *(const bf16x8*)(XL1 + (size_t)s2 * NCOL1 + 1024 + cb);
    }
    float mjs[8], mjp[8], ps_ = 0.f, pp_ = 0.f;
#pragma unroll
    for (int j = 0; j < 8; j++) {
      mjs[j] = (float)cs[j];
      float t = mjs[j] + xs[j];
      t = (t > 0.f) ? t : 0.2f * t;
      ps_ = fmaf(as_[j], t, ps_);
      mjp[j] = (float)cp[j];
      float u = mjp[j] + xp[j];
      u = (u > 0.f) ? u : 0.2f * u;
      pp_ = fmaf(ap_[j], u, pp_);
    }
#pragma unroll
    for (int w = 1; w < 16; w <<= 1) { ps_ += __shfl_xor(ps_, w); pp_ += __shfl_xor(pp_, w); }
    float nms = fmaxf(Ms, ps_);
    float fs = __expf(Ms - nms), ws_ = __expf(ps_ - nms);
    Ss = Ss * fs + ws_;
    float nmp = fmaxf(Mp, pp_);
    float fp = __expf(Mp - nmp), wp_ = __expf(pp_ - nmp);
    Sp = Sp * fp + wp_;
#pragma unroll
    for (int j = 0; j < 8; j++) {
      aggs[j] = aggs[j] * fs + ws_ * mjs[j];
      aggp[j] = aggp[j] * fp + wp_ * mjp[j];
    }
    Ms = nms; Mp = nmp;
  }
  float invs = 1.f / Ss, invp = 1.f / Sp;
  u16x8 hs, hp;
#pragma unroll
  for (int j = 0; j < 8; j++) {
    float v = fmaxf(aggs[j] * invs + b_s[cb + j], 0.f);   // relu on s-branch
    hs[j] = f2bf(v);
    float u = aggp[j] * invp + b_p[cb + j];
    hp[j] = f2bf(u);
  }
  *(u16x8*)(A2s + (size_t)n * LDA2 + cb) = hs;
  *(u16x8*)(A2p + (size_t)n * LDA2 + cb) = hp;
}

// ---------------- layer-2 edge softmax+aggregate+epilogue: BOTH branches per wave + prefetch ----

__global__ __launch_bounds__(256)
void edge_agg2(const float* __restrict__ C2s, const float* __restrict__ C2p,
               const int* __restrict__ row_ptr, const int* __restrict__ csr_src,
               const float* __restrict__ att_s, const float* __restrict__ att_p,
               const float* __restrict__ b_s, const float* __restrict__ b_p,
               float* __restrict__ out) {
  int n = (blockIdx.x * 256 + threadIdx.x) >> 6;
  if (n >= NN) return;
  int lane = threadIdx.x & 63;
  float xrs = C2s[(size_t)n * 128 + 64 + lane];
  float xrp = C2p[(size_t)n * 128 + 64 + lane];
  float ats = att_s[lane], atp = att_p[lane];
  float Ms = -1e30f, Ss = 0.f, ags = 0.f;
  float Mp = -1e30f, Sp = 0.f, agp = 0.f;
  int p0 = row_ptr[n], pe = row_ptr[n + 1];
  int src = csr_src[p0];
  float ms = C2s[(size_t)src * 128 + lane];
  float mp = C2p[(size_t)src * 128 + lane];
  for (int p = p0; p < pe; ++p) {
    float cs = ms, cp = mp;
    if (p + 1 < pe) {
      int s2 = csr_src[p + 1];
      ms = C2s[(size_t)s2 * 128 + lane];
      mp = C2p[(size_t)s2 * 128 + lane];
    }
    float t = cs + xrs; t = (t > 0.f) ? t : 0.2f * t;
    float u = cp + xrp; u = (u > 0.f) ? u : 0.2f * u;
    float ps_ = ats * t, pp_ = atp * u;
#pragma unroll
    for (int w = 1; w < 64; w <<= 1) { ps_ += __shfl_xor(ps_, w); pp_ += __shfl_xor(pp_, w); }
    float nms = fmaxf(Ms, ps_);
    float fs = __expf(Ms - nms), ws_ = __expf(ps_ - nms);
    Ss = Ss * fs + ws_; ags = ags * fs + ws_ * cs; Ms = nms;
    float nmp = fmaxf(Mp, pp_);
    float fp = __expf(Mp - nmp), wp_ = __expf(pp_ - nmp);
    Sp = Sp * fp + wp_; agp = agp * fp + wp_ * cp; Mp = nmp;
  }
  float vs = ags / Ss + b_s[lane];
  float vp = agp / Sp + b_p[lane];
  if (lane < 32) {
    out[(size_t)n * 64 + lane] = vs;                                 // mu_s
    out[(size_t)n * 64 + 32 + lane] = vp;                            // mu_p
  } else {
    float sps = fmaxf(vs, 0.f) + log1pf(__expf(-fabsf(vs))) + 1e-6f;
    float spp = fmaxf(vp, 0.f) + log1pf(__expf(-fabsf(vp))) + 1e-6f;
    out[(size_t)MU_SZ + n * 64 + (lane - 32)] = sps;                 // sig_s
    out[(size_t)MU_SZ + n * 64 + 32 + (lane - 32)] = spp;            // sig_p
  }
}

// ---------------- host ----------------

extern "C" void kernel_launch(void* const* d_in, const int* in_sizes, int n_in,
                              void* d_out, int out_size, void* d_ws, size_t ws_size,
                              hipStream_t stream) {
  const float* x      = (const float*)d_in[0];
  const int*   ei     = (const int*)d_in[1];
  const float* Wl_s1  = (const float*)d_in[2];
  const float* Wr_s1  = (const float*)d_in[3];
  const float* att_s1 = (const float*)d_in[4];
  const float* b_s1   = (const float*)d_in[5];
  const float* Wl_s2  = (const float*)d_in[6];
  const float* Wr_s2  = (const float*)d_in[7];
  const float* att_s2 = (const float*)d_in[8];
  const float* b_s2   = (const float*)d_in[9];
  const float* Wl_p1  = (const float*)d_in[10];
  const float* Wr_p1  = (const float*)d_in[11];
  const float* att_p1 = (const float*)d_in[12];
  const float* b_p1   = (const float*)d_in[13];
  const float* Wl_p2  = (const float*)d_in[14];
  const float* Wr_p2  = (const float*)d_in[15];
  const float* att_p2 = (const float*)d_in[16];
  const float* b_p2   = (const float*)d_in[17];

  char* ws = (char*)d_ws;
  // Region R0 [0, 124.3MB): Xb during GEMM1; reused afterwards for layer-2 buffers.
  unsigned short* Xb   = (unsigned short*)(ws + 0);           // 20224*3072*2 = 124,256,256
  unsigned short* A2s  = (unsigned short*)(ws + 0);           // 20096*512*2 = 20,578,304
  unsigned short* A2p  = (unsigned short*)(ws + 20578304);    // 20,578,304
  float*          C2s  = (float*)(ws + 41156608);             // 10,240,000
  float*          C2p  = (float*)(ws + 51396608);             // 10,240,000
  unsigned short* B2s  = (unsigned short*)(ws + 61636608);    // 131,072
  unsigned short* B2p  = (unsigned short*)(ws + 61767680);    // 131,072
  unsigned short* Wp   = (unsigned short*)(ws + 124256256);   // 12,582,912
  unsigned short* XL1  = (unsigned short*)(ws + 136839168);   // 20224*2048*2 = 82,837,504
  int* counts  = (int*)(ws + 219676672);
  int* fill    = (int*)(ws + 219756672);
  int* row_ptr = (int*)(ws + 219836672);
  int* csr_src = (int*)(ws + 219916688);                      // ends ~221.3 MB

  hipMemsetAsync(counts, 0, NN * sizeof(int), stream);
  hipMemsetAsync(fill, 0, NN * sizeof(int), stream);

  k_convert_x<<<30336, 256, 0, stream>>>(x, Xb);
  k_pack_w1<<<dim3(48, 32), 256, 0, stream>>>(Wl_s1, Wr_s1, Wl_p1, Wr_p1, Wp);
  k_count<<<(ETOT + 255) / 256, 256, 0, stream>>>(ei, counts);
  k_scan<<<1, 1024, 0, stream>>>(counts, row_ptr);
  k_scatter<<<(ETOT + 255) / 256, 256, 0, stream>>>(ei, row_ptr, fill, csr_src);

  // XL1[n, 0:512|512:1024|1024:1536|1536:2048] = x@{Wl_s1|Wr_s1|Wl_p1|Wr_p1}, bf16
  gemm256<<<632, 512, 0, stream>>>(Xb, Wp, XL1);

  k_pack_w2b<<<512, 256, 0, stream>>>(Wl_s2, Wr_s2, Wl_p2, Wr_p2, B2s, B2p);

  edge_agg1<<<5000, 256, 0, stream>>>(XL1, row_ptr, csr_src, att_s1, att_p1, b_s1, b_p1, A2s, A2p);

  // layer-2: both branches, one launch, K=512
  gemm_l2<<<dim3(157, 2), 256, 0, stream>>>(A2s, B2s, C2s, A2p, B2p, C2p);

  edge_agg2<<<5000, 256, 0, stream>>>(C2s, C2p, row_ptr, csr_src, att_s2, att_p2, b_s2, b_p2, (float*)d_out);
}

// Round 13
// 587.167 us; speedup vs baseline: 1.1099x; 1.0267x over previous
//
#include <hip/hip_runtime.h>
#include <cstdint>

// Problem constants
#define NN     20000      // nodes
#define NE     320000     // input edges
#define ETOT   340000     // edges + self loops
#define K1R    3000       // in_dim
#define K1     3072       // padded K for GEMM1
#define NPAD   20224      // 79*256 padded rows (256-tile GEMM1)
#define NCOL1  2048       // 4 x 512 packed outputs (xl_s|xr_s|xl_p|xr_p)
#define LDA2   512        // layer-2 A row (plain bf16)
#define MU_SZ  1280000    // 20000*64

typedef __bf16 bf16x8 __attribute__((ext_vector_type(8)));
typedef float f32x4 __attribute__((ext_vector_type(4)));
typedef unsigned short u16x8 __attribute__((ext_vector_type(8)));

__device__ inline unsigned short f2bf(float f) {
  union { float f; unsigned u; } v; v.f = f;
  unsigned r = v.u + 0x7FFFu + ((v.u >> 16) & 1u);
  return (unsigned short)(r >> 16);
}
__device__ inline float bf2f(unsigned short h) {
  union { unsigned u; float f; } v; v.u = ((unsigned)h) << 16;
  return v.f;
}

typedef const __attribute__((address_space(1))) void* gas1_t;
typedef __attribute__((address_space(3))) void* las3_t;
__device__ inline void llds16(const void* g, void* l) {
  __builtin_amdgcn_global_load_lds((gas1_t)(uintptr_t)g,
                                   (las3_t)(uint32_t)(uintptr_t)l, 16, 0, 0);
}

// ---------------- mega-prep: pack_w1 | count | convert_x in one launch ----------
// NOTE: pack_w2b is NOT fused here — B2s/B2p alias Xb's region and may only be
// written AFTER gemm256 has consumed Xb (R12's fusion corrupted Xb -> absmax 66).
#define PB_PW1  1536                       // pack_w1: 48 x 32 blocks
#define PB_CNT  (PB_PW1 + 1329)            // count: ceil(ETOT/256)
#define PB_CVT  (PB_CNT + 30336)           // convert: NPAD*384/256

__global__ __launch_bounds__(256)
void k_prep(const float* __restrict__ X, unsigned short* __restrict__ Xb,
            const float* __restrict__ W0, const float* __restrict__ W1,
            const float* __restrict__ W2, const float* __restrict__ W3,
            unsigned short* __restrict__ Wp,
            const int* __restrict__ ei, int* __restrict__ counts) {
  __shared__ float tile[64][65];
  int b = blockIdx.x, tid = threadIdx.x;

  if (b < PB_PW1) {
    // ---- pack_w1: 4x [3000,512] f32 -> Wp[2048][3072] bf16 (B^T), zero-pad k>=3000
    int k0 = (b % 48) * 64, n0 = (b / 48) * 64;
    int m = n0 >> 9, c0 = n0 & 511;
    const float* W = (m == 0) ? W0 : (m == 1) ? W1 : (m == 2) ? W2 : W3;
    int tx = tid & 63, ty = tid >> 6;
#pragma unroll
    for (int rep = 0; rep < 16; rep++) {
      int i = ty + rep * 4;
      int k = k0 + i;
      tile[i][tx] = (k < K1R) ? W[(size_t)k * 512 + c0 + tx] : 0.f;
    }
    __syncthreads();
#pragma unroll
    for (int rep = 0; rep < 16; rep++) {
      int i = ty + rep * 4;
      Wp[(size_t)(n0 + i) * K1 + k0 + tx] = f2bf(tile[tx][i]);
    }
  } else if (b < PB_CNT) {
    // ---- degree count (self-loops implicit)
    int e = (b - PB_PW1) * 256 + tid;
    if (e < ETOT) {
      int dst = (e < NE) ? ei[NE + e] : (e - NE);
      atomicAdd(&counts[dst], 1);
    }
  } else {
    // ---- convert x f32 -> Xb bf16 [NPAD][3072], zero-pad
    const int CH = K1 / 8;
    int idx = (b - PB_CNT) * 256 + tid;
    if (idx >= NPAD * CH) return;
    int r = idx / CH, c8 = (idx % CH) * 8;
    u16x8 o;
    if (r < NN && c8 < K1R) {
      const float4* p = (const float4*)(X + (size_t)r * K1R + c8);
      float4 a = p[0], bb = p[1];
      o[0]=f2bf(a.x); o[1]=f2bf(a.y); o[2]=f2bf(a.z); o[3]=f2bf(a.w);
      o[4]=f2bf(bb.x); o[5]=f2bf(bb.y); o[6]=f2bf(bb.z); o[7]=f2bf(bb.w);
    } else {
#pragma unroll
      for (int j = 0; j < 8; j++) o[j] = 0;
    }
    *(u16x8*)(Xb + (size_t)r * K1 + c8) = o;
  }
}

// ---------------- pack layer-2 weights (launched AFTER gemm256; B2 aliases Xb) ----------

__global__ __launch_bounds__(256)
void k_pack_w2b(const float* __restrict__ Wl_s, const float* __restrict__ Wr_s,
                const float* __restrict__ Wl_p, const float* __restrict__ Wr_p,
                unsigned short* __restrict__ B2s, unsigned short* __restrict__ B2p) {
  int gidx = blockIdx.x * 256 + threadIdx.x;   // grid 512 -> 131072
  int br = gidx >> 16, idx = gidx & 65535;
  const float* Wl = br ? Wl_p : Wl_s;
  const float* Wr = br ? Wr_p : Wr_s;
  unsigned short* B2 = br ? B2p : B2s;
  int n = idx >> 9, k = idx & 511;
  float v = (n < 64) ? Wl[(size_t)k * 64 + n] : Wr[(size_t)k * 64 + (n - 64)];
  B2[idx] = f2bf(v);
}

// ---------------- CSR scan + scatter ----------------

__global__ void k_scan(const int* __restrict__ counts, int* __restrict__ row_ptr) {
  __shared__ int part[1024];
  int t = threadIdx.x;
  int base = t * 20;
  int loc[20];
  int s = 0;
#pragma unroll
  for (int i = 0; i < 20; i++) {
    int idx = base + i;
    loc[i] = s;
    s += (idx < NN) ? counts[idx] : 0;
  }
  part[t] = s;
  __syncthreads();
  for (int off = 1; off < 1024; off <<= 1) {
    int v = (t >= off) ? part[t - off] : 0;
    __syncthreads();
    part[t] += v;
    __syncthreads();
  }
  int pre = (t > 0) ? part[t - 1] : 0;
#pragma unroll
  for (int i = 0; i < 20; i++) {
    int idx = base + i;
    if (idx <= NN) row_ptr[idx] = pre + loc[i];
  }
}

// scatter using counts as down-counting cursor (no separate fill array):
// pos = row_ptr[d] + (old_count - 1); segment order permuted (softmax order-invariant).
// counts ends at 0 -> deterministic across graph replays (memset re-zeros anyway).
__global__ __launch_bounds__(256)
void k_scatter(const int* __restrict__ ei, const int* __restrict__ row_ptr,
               int* __restrict__ counts, int* __restrict__ csr_src) {
  int e = blockIdx.x * 256 + threadIdx.x;
  if (e >= ETOT) return;
  int s_, d_;
  if (e < NE) { s_ = ei[e]; d_ = ei[NE + e]; } else { s_ = d_ = e - NE; }
  int old = atomicSub(&counts[d_], 1);
  csr_src[row_ptr[d_] + old - 1] = s_;
}

// ---------------- GEMM1: 256x256, role-staggered waves, 1 barrier per K-tile ----------------
// (best measured variant: R6, 298-303 us — FROZEN)

#define NT1 48

#define STAGE_ONE do { \
  if (sctr < 4 * NT1) { \
    int ts_ = sctr >> 2, u_ = sctr & 3, sb_ = ts_ & 1; \
    const unsigned short* gb_; char* lb_; int rb_; \
    if (u_ == 0)      { gb_ = A; rb_ = bmBase + 128; lb_ = lds + (sb_*2+1)*16384; } \
    else if (u_ == 1) { gb_ = B; rb_ = bnBase + 128; lb_ = lds + 65536 + (sb_*2+1)*16384; } \
    else if (u_ == 2) { gb_ = B; rb_ = bnBase;       lb_ = lds + 65536 + (sb_*2+0)*16384; } \
    else              { gb_ = A; rb_ = bmBase;       lb_ = lds + (sb_*2+0)*16384; } \
    const unsigned short* g0_ = gb_ + (size_t)(rb_ + trow) * 3072 + ts_ * 64 + scol; \
    llds16(g0_, lb_ + wid * 1024); \
    llds16(g0_ + (size_t)64 * 3072, lb_ + 8192 + wid * 1024); \
    sctr++; \
  } \
} while (0)

#define RDA(DST, BASE) do { \
  _Pragma("unroll") \
  for (int mi = 0; mi < 2; mi++) { \
    int r_ = rw * 32 + mi * 16 + l15; \
    DST[0][mi] = *(const bf16x8*)((BASE) + r_ * 128 + sw0); \
    DST[1][mi] = *(const bf16x8*)((BASE) + r_ * 128 + sw1); \
  } \
} while (0)

#define RDB(DST, BASE) do { \
  _Pragma("unroll") \
  for (int ni = 0; ni < 4; ni++) { \
    int r_ = cw * 64 + ni * 16 + l15; \
    DST[0][ni] = *(const bf16x8*)((BASE) + r_ * 128 + sw0); \
    DST[1][ni] = *(const bf16x8*)((BASE) + r_ * 128 + sw1); \
  } \
} while (0)

#define MF(MH, NH, AV, BV) do { \
  __builtin_amdgcn_s_setprio(1); \
  _Pragma("unroll") \
  for (int mi = 0; mi < 2; mi++) \
    _Pragma("unroll") \
    for (int ni = 0; ni < 4; ni++) { \
      acc[MH][NH][mi][ni] = __builtin_amdgcn_mfma_f32_16x16x32_bf16(AV[0][mi], BV[0][ni], acc[MH][NH][mi][ni], 0, 0, 0); \
      acc[MH][NH][mi][ni] = __builtin_amdgcn_mfma_f32_16x16x32_bf16(AV[1][mi], BV[1][ni], acc[MH][NH][mi][ni], 0, 0, 0); \
    } \
  __builtin_amdgcn_s_setprio(0); \
} while (0)

__global__ __launch_bounds__(512, 2)
void gemm256(const unsigned short* __restrict__ A, const unsigned short* __restrict__ B,
             unsigned short* __restrict__ C) {
  __shared__ char lds[131072];
  int tid = threadIdx.x, wid = tid >> 6, lane = tid & 63;
  int l15 = lane & 15;
  int rw = wid & 3, cw = wid >> 2;
  int role = (wid >> 2) & 1;
  int bid = blockIdx.x;
  int bn = bid & 7, bm = bid >> 3;
  int bmBase = bm * 256, bnBase = bn * 256;
  int trow = tid >> 3;
  int scol = ((tid & 7) ^ ((tid >> 3) & 7)) * 8;
  int sw0 = (((lane >> 4) + 0) ^ (lane & 7)) * 16;
  int sw1 = (((lane >> 4) + 4) ^ (lane & 7)) * 16;
  f32x4 acc[2][2][2][4] = {};

  int sctr = 0;
  for (int i = 0; i < 4; i++) STAGE_ONE;
  asm volatile("s_waitcnt vmcnt(0)" ::: "memory");
  __builtin_amdgcn_s_barrier();
  asm volatile("" ::: "memory");

  for (int t = 0; t < NT1; t++) {
    int buf = t & 1;
    const char* A0h = lds + (buf * 2 + 0) * 16384;
    const char* A1h = lds + (buf * 2 + 1) * 16384;
    const char* B0h = lds + 65536 + (buf * 2 + 0) * 16384;
    const char* B1h = lds + 65536 + (buf * 2 + 1) * 16384;
    bf16x8 a0[2][2], a1[2][2], b0[2][4], b1[2][4];

    if (role == 0) {
      STAGE_ONE;
      RDA(a0, A0h); RDB(b0, B0h);
      MF(0, 0, a0, b0);
      STAGE_ONE;
      RDA(a1, A1h);
      MF(1, 0, a1, b0);
      STAGE_ONE;
      RDB(b1, B1h);
      MF(1, 1, a1, b1);
      STAGE_ONE;
      MF(0, 1, a0, b1);
    } else {
      STAGE_ONE;
      RDA(a1, A1h); RDB(b1, B1h);
      MF(1, 1, a1, b1);
      STAGE_ONE;
      RDA(a0, A0h);
      MF(0, 1, a0, b1);
      STAGE_ONE;
      RDB(b0, B0h);
      MF(0, 0, a0, b0);
      STAGE_ONE;
      MF(1, 0, a1, b0);
    }
    asm volatile("s_waitcnt vmcnt(0)" ::: "memory");
    __builtin_amdgcn_s_barrier();
    asm volatile("" ::: "memory");
  }

  unsigned short (*sq)[128] = (unsigned short (*)[128])lds;
#pragma unroll
  for (int mh = 0; mh < 2; mh++)
#pragma unroll
    for (int nh = 0; nh < 2; nh++) {
      __syncthreads();
#pragma unroll
      for (int mi = 0; mi < 2; mi++)
#pragma unroll
        for (int ni = 0; ni < 4; ni++)
#pragma unroll
          for (int r = 0; r < 4; r++)
            sq[rw * 32 + mi * 16 + (lane >> 4) * 4 + r][cw * 64 + ni * 16 + l15] =
                f2bf(acc[mh][nh][mi][ni][r]);
      __syncthreads();
#pragma unroll
      for (int it = 0; it < 4; it++) {
        int idx = it * 512 + tid;
        int row = idx >> 4, ch = idx & 15;
        *(u16x8*)(C + (size_t)(bmBase + mh * 128 + row) * NCOL1 + bnBase + nh * 128 + ch * 8) =
            *(const u16x8*)&sq[row][ch * 8];
      }
    }
}

// ---------------- layer-2 GEMM (128-tile m97 structure), both branches, K=512 ----------------

__global__ __launch_bounds__(256)
void gemm_l2(const unsigned short* __restrict__ As, const unsigned short* __restrict__ Bs,
             float* __restrict__ Cs,
             const unsigned short* __restrict__ Ap, const unsigned short* __restrict__ Bp,
             float* __restrict__ Cp) {
  const int K = LDA2, lda = LDA2, ldb = LDA2, ldc = 128, mreal = NN;
  const unsigned short* A = blockIdx.y ? Ap : As;
  const unsigned short* B = blockIdx.y ? Bp : Bs;
  float* C = blockIdx.y ? Cp : Cs;
  __shared__ char smem_raw[16384];
  unsigned short* sA = (unsigned short*)smem_raw;
  unsigned short* sB = sA + 128 * 32;
  int bm = blockIdx.x;
  int tid = threadIdx.x, wid = tid >> 6, lane = tid & 63;
  int wr = wid >> 1, wc = wid & 1;
  f32x4 acc[4][4] = {};

  int ar = 32 * wid + (lane >> 2);
  int acol = (lane & 3) * 8;
  const unsigned short* Ag = A + (size_t)(bm * 128 + ar) * lda + acol;
  const unsigned short* Bg = B + (size_t)ar * ldb + acol;
  unsigned short* la0 = sA + (wid * 2) * 512;
  unsigned short* lb0 = sB + (wid * 2) * 512;
  int frow = lane & 15, koff = (lane >> 4) * 8;

  for (int kt = 0; kt < K; kt += 32) {
    llds16(Ag + kt, la0);
    llds16(Ag + kt + (size_t)16 * lda, la0 + 512);
    llds16(Bg + kt, lb0);
    llds16(Bg + kt + (size_t)16 * ldb, lb0 + 512);
    __syncthreads();
    bf16x8 af[4], bfr[4];
#pragma unroll
    for (int mi = 0; mi < 4; mi++)
      af[mi] = *(const bf16x8*)(sA + (wr * 64 + mi * 16 + frow) * 32 + koff);
#pragma unroll
    for (int ni = 0; ni < 4; ni++)
      bfr[ni] = *(const bf16x8*)(sB + (wc * 64 + ni * 16 + frow) * 32 + koff);
#pragma unroll
    for (int mi = 0; mi < 4; mi++)
#pragma unroll
      for (int ni = 0; ni < 4; ni++)
        acc[mi][ni] = __builtin_amdgcn_mfma_f32_16x16x32_bf16(af[mi], bfr[ni], acc[mi][ni], 0, 0, 0);
    __syncthreads();
  }

#pragma unroll
  for (int mi = 0; mi < 4; mi++) {
    int grow0 = bm * 128 + wr * 64 + mi * 16 + (lane >> 4) * 4;
#pragma unroll
    for (int ni = 0; ni < 4; ni++) {
      int gcol = wc * 64 + ni * 16 + (lane & 15);
#pragma unroll
      for (int r = 0; r < 4; r++) {
        int grow = grow0 + r;
        if (grow < mreal) C[(size_t)grow * ldc + gcol] = acc[mi][ni][r];
      }
    }
  }
}

// ---------------- layer-1 edge softmax+aggregate: BOTH branches per wave + prefetch -------

__global__ __launch_bounds__(256)
void edge_agg1(const unsigned short* __restrict__ XL1,
               const int* __restrict__ row_ptr, const int* __restrict__ csr_src,
               const float* __restrict__ att_s, const float* __restrict__ att_p,
               const float* __restrict__ b_s, const float* __restrict__ b_p,
               unsigned short* __restrict__ A2s, unsigned short* __restrict__ A2p) {
  int n = (blockIdx.x * 256 + threadIdx.x) >> 6;
  if (n >= NN) return;
  int lane = threadIdx.x & 63;
  int cb = lane * 8;
  float xs[8], xp[8], as_[8], ap_[8], aggs[8], aggp[8];
  {
    bf16x8 xsv = *(const bf16x8*)(XL1 + (size_t)n * NCOL1 + 512 + cb);
    bf16x8 xpv = *(const bf16x8*)(XL1 + (size_t)n * NCOL1 + 1536 + cb);
    float4 a0 = *(const float4*)(att_s + cb), a1 = *(const float4*)(att_s + cb + 4);
    float4 a2 = *(const float4*)(att_p + cb), a3 = *(const float4*)(att_p + cb + 4);
    as_[0]=a0.x; as_[1]=a0.y; as_[2]=a0.z; as_[3]=a0.w; as_[4]=a1.x; as_[5]=a1.y; as_[6]=a1.z; as_[7]=a1.w;
    ap_[0]=a2.x; ap_[1]=a2.y; ap_[2]=a2.z; ap_[3]=a2.w; ap_[4]=a3.x; ap_[5]=a3.y; ap_[6]=a3.z; ap_[7]=a3.w;
#pragma unroll
    for (int j = 0; j < 8; j++) { xs[j] = (float)xsv[j]; xp[j] = (float)xpv[j]; aggs[j] = 0.f; aggp[j] = 0.f; }
  }
  float Ms = -1e30f, Ss = 0.f, Mp = -1e30f, Sp = 0.f;
  int p0 = row_ptr[n], pe = row_ptr[n + 1];
  int src = csr_src[p0];
  bf16x8 ms = *(const bf16x8*)(XL1 + (size_t)src * NCOL1 + cb);
  bf16x8 mp = *(const bf16x8*)(XL1 + (size_t)src * NCOL1 + 1024 + cb);
  for (int p = p0; p < pe; ++p) {
    bf16x8 cs = ms, cp = mp;
    if (p + 1 < pe) {
      int s2 = csr_src[p + 1];
      ms = *(const bf16x8*)(XL1 + (size_t)s2 * NCOL1 + cb);
      mp = *(const bf16x8*)(XL1 + (size_t)s2 * NCOL1 + 1024 + cb);
    }
    float mjs[8], mjp[8], ps_ = 0.f, pp_ = 0.f;
#pragma unroll
    for (int j = 0; j < 8; j++) {
      mjs[j] = (float)cs[j];
      float t = mjs[j] + xs[j];
      t = (t > 0.f) ? t : 0.2f * t;
      ps_ = fmaf(as_[j], t, ps_);
      mjp[j] = (float)cp[j];
      float u = mjp[j] + xp[j];
      u = (u > 0.f) ? u : 0.2f * u;
      pp_ = fmaf(ap_[j], u, pp_);
    }
#pragma unroll
    for (int w = 1; w < 16; w <<= 1) { ps_ += __shfl_xor(ps_, w); pp_ += __shfl_xor(pp_, w); }
    float nms = fmaxf(Ms, ps_);
    float fs = __expf(Ms - nms), ws_ = __expf(ps_ - nms);
    Ss = Ss * fs + ws_;
    float nmp = fmaxf(Mp, pp_);
    float fp = __expf(Mp - nmp), wp_ = __expf(pp_ - nmp);
    Sp = Sp * fp + wp_;
#pragma unroll
    for (int j = 0; j < 8; j++) {
      aggs[j] = aggs[j] * fs + ws_ * mjs[j];
      aggp[j] = aggp[j] * fp + wp_ * mjp[j];
    }
    Ms = nms; Mp = nmp;
  }
  float invs = 1.f / Ss, invp = 1.f / Sp;
  u16x8 hs, hp;
#pragma unroll
  for (int j = 0; j < 8; j++) {
    float v = fmaxf(aggs[j] * invs + b_s[cb + j], 0.f);
    hs[j] = f2bf(v);
    float u = aggp[j] * invp + b_p[cb + j];
    hp[j] = f2bf(u);
  }
  *(u16x8*)(A2s + (size_t)n * LDA2 + cb) = hs;
  *(u16x8*)(A2p + (size_t)n * LDA2 + cb) = hp;
}

// ---------------- layer-2 edge softmax+aggregate+epilogue: BOTH branches per wave + prefetch ----

__global__ __launch_bounds__(256)
void edge_agg2(const float* __restrict__ C2s, const float* __restrict__ C2p,
               const int* __restrict__ row_ptr, const int* __restrict__ csr_src,
               const float* __restrict__ att_s, const float* __restrict__ att_p,
               const float* __restrict__ b_s, const float* __restrict__ b_p,
               float* __restrict__ out) {
  int n = (blockIdx.x * 256 + threadIdx.x) >> 6;
  if (n >= NN) return;
  int lane = threadIdx.x & 63;
  float xrs = C2s[(size_t)n * 128 + 64 + lane];
  float xrp = C2p[(size_t)n * 128 + 64 + lane];
  float ats = att_s[lane], atp = att_p[lane];
  float Ms = -1e30f, Ss = 0.f, ags = 0.f;
  float Mp = -1e30f, Sp = 0.f, agp = 0.f;
  int p0 = row_ptr[n], pe = row_ptr[n + 1];
  int src = csr_src[p0];
  float ms = C2s[(size_t)src * 128 + lane];
  float mp = C2p[(size_t)src * 128 + lane];
  for (int p = p0; p < pe; ++p) {
    float cs = ms, cp = mp;
    if (p + 1 < pe) {
      int s2 = csr_src[p + 1];
      ms = C2s[(size_t)s2 * 128 + lane];
      mp = C2p[(size_t)s2 * 128 + lane];
    }
    float t = cs + xrs; t = (t > 0.f) ? t : 0.2f * t;
    float u = cp + xrp; u = (u > 0.f) ? u : 0.2f * u;
    float ps_ = ats * t, pp_ = atp * u;
#pragma unroll
    for (int w = 1; w < 64; w <<= 1) { ps_ += __shfl_xor(ps_, w); pp_ += __shfl_xor(pp_, w); }
    float nms = fmaxf(Ms, ps_);
    float fs = __expf(Ms - nms), ws_ = __expf(ps_ - nms);
    Ss = Ss * fs + ws_; ags = ags * fs + ws_ * cs; Ms = nms;
    float nmp = fmaxf(Mp, pp_);
    float fp = __expf(Mp - nmp), wp_ = __expf(pp_ - nmp);
    Sp = Sp * fp + wp_; agp = agp * fp + wp_ * cp; Mp = nmp;
  }
  float vs = ags / Ss + b_s[lane];
  float vp = agp / Sp + b_p[lane];
  if (lane < 32) {
    out[(size_t)n * 64 + lane] = vs;
    out[(size_t)n * 64 + 32 + lane] = vp;
  } else {
    float sps = fmaxf(vs, 0.f) + log1pf(__expf(-fabsf(vs))) + 1e-6f;
    float spp = fmaxf(vp, 0.f) + log1pf(__expf(-fabsf(vp))) + 1e-6f;
    out[(size_t)MU_SZ + n * 64 + (lane - 32)] = sps;
    out[(size_t)MU_SZ + n * 64 + 32 + (lane - 32)] = spp;
  }
}

// ---------------- host ----------------

extern "C" void kernel_launch(void* const* d_in, const int* in_sizes, int n_in,
                              void* d_out, int out_size, void* d_ws, size_t ws_size,
                              hipStream_t stream) {
  const float* x      = (const float*)d_in[0];
  const int*   ei     = (const int*)d_in[1];
  const float* Wl_s1  = (const float*)d_in[2];
  const float* Wr_s1  = (const float*)d_in[3];
  const float* att_s1 = (const float*)d_in[4];
  const float* b_s1   = (const float*)d_in[5];
  const float* Wl_s2  = (const float*)d_in[6];
  const float* Wr_s2  = (const float*)d_in[7];
  const float* att_s2 = (const float*)d_in[8];
  const float* b_s2   = (const float*)d_in[9];
  const float* Wl_p1  = (const float*)d_in[10];
  const float* Wr_p1  = (const float*)d_in[11];
  const float* att_p1 = (const float*)d_in[12];
  const float* b_p1   = (const float*)d_in[13];
  const float* Wl_p2  = (const float*)d_in[14];
  const float* Wr_p2  = (const float*)d_in[15];
  const float* att_p2 = (const float*)d_in[16];
  const float* b_p2   = (const float*)d_in[17];

  char* ws = (char*)d_ws;
  unsigned short* Xb   = (unsigned short*)(ws + 0);           // 20224*3072*2 = 124,256,256
  unsigned short* A2s  = (unsigned short*)(ws + 0);           // 20096*512*2 = 20,578,304 (after Xb dead)
  unsigned short* A2p  = (unsigned short*)(ws + 20578304);    // 20,578,304
  float*          C2s  = (float*)(ws + 41156608);             // 10,240,000
  float*          C2p  = (float*)(ws + 51396608);             // 10,240,000
  unsigned short* B2s  = (unsigned short*)(ws + 61636608);    // 131,072 (aliases Xb; written post-gemm256)
  unsigned short* B2p  = (unsigned short*)(ws + 61767680);    // 131,072
  unsigned short* Wp   = (unsigned short*)(ws + 124256256);   // 12,582,912
  unsigned short* XL1  = (unsigned short*)(ws + 136839168);   // 20224*2048*2 = 82,837,504
  int* counts  = (int*)(ws + 219676672);                      // 80,000
  int* row_ptr = (int*)(ws + 219836672);                      // 80,004
  int* csr_src = (int*)(ws + 219916688);                      // 1,360,000

  hipMemsetAsync(counts, 0, NN * sizeof(int), stream);

  k_prep<<<PB_CVT, 256, 0, stream>>>(x, Xb, Wl_s1, Wr_s1, Wl_p1, Wr_p1, Wp, ei, counts);
  k_scan<<<1, 1024, 0, stream>>>(counts, row_ptr);
  k_scatter<<<(ETOT + 255) / 256, 256, 0, stream>>>(ei, row_ptr, counts, csr_src);

  // XL1[n, 0:512|512:1024|1024:1536|1536:2048] = x@{Wl_s1|Wr_s1|Wl_p1|Wr_p1}, bf16
  gemm256<<<632, 512, 0, stream>>>(Xb, Wp, XL1);

  k_pack_w2b<<<512, 256, 0, stream>>>(Wl_s2, Wr_s2, Wl_p2, Wr_p2, B2s, B2p);

  edge_agg1<<<5000, 256, 0, stream>>>(XL1, row_ptr, csr_src, att_s1, att_p1, b_s1, b_p1, A2s, A2p);

  gemm_l2<<<dim3(157, 2), 256, 0, stream>>>(A2s, B2s, C2s, A2p, B2p, C2p);

  edge_agg2<<<5000, 256, 0, stream>>>(C2s, C2p, row_ptr, csr_src, att_s2, att_p2, b_s2, b_p2, (float*)d_out);
}

// Round 14
// 585.155 us; speedup vs baseline: 1.1138x; 1.0034x over previous
//
#include <hip/hip_runtime.h>
#include <cstdint>

// Problem constants
#define NN     20000      // nodes
#define NE     320000     // input edges
#define ETOT   340000     // edges + self loops
#define K1R    3000       // in_dim
#define K1     3072       // padded K for GEMM1
#define NPAD   20224      // 79*256 padded rows (256-tile GEMM1)
#define NCOL1  2048       // 4 x 512 packed outputs (xl_s|xr_s|xl_p|xr_p)
#define LDA2   512        // layer-2 A row (plain bf16)
#define MU_SZ  1280000    // 20000*64

typedef __bf16 bf16x8 __attribute__((ext_vector_type(8)));
typedef float f32x4 __attribute__((ext_vector_type(4)));
typedef unsigned short u16x8 __attribute__((ext_vector_type(8)));

__device__ inline unsigned short f2bf(float f) {
  union { float f; unsigned u; } v; v.f = f;
  unsigned r = v.u + 0x7FFFu + ((v.u >> 16) & 1u);
  return (unsigned short)(r >> 16);
}
__device__ inline float bf2f(unsigned short h) {
  union { unsigned u; float f; } v; v.u = ((unsigned)h) << 16;
  return v.f;
}

typedef const __attribute__((address_space(1))) void* gas1_t;
typedef __attribute__((address_space(3))) void* las3_t;
__device__ inline void llds16(const void* g, void* l) {
  __builtin_amdgcn_global_load_lds((gas1_t)(uintptr_t)g,
                                   (las3_t)(uint32_t)(uintptr_t)l, 16, 0, 0);
}

// ---------------- mega-prep: pack_w1 | count | convert_x in one launch ----------
// NOTE: pack_w2b is NOT fused here — B2s/B2p alias Xb's region and may only be
// written AFTER gemm256 has consumed Xb (R12's fusion corrupted Xb -> absmax 66).
#define PB_PW1  1536                       // pack_w1: 48 x 32 blocks
#define PB_CNT  (PB_PW1 + 1329)            // count: ceil(ETOT/256)
#define PB_CVT  (PB_CNT + 30336)           // convert: NPAD*384/256

__global__ __launch_bounds__(256)
void k_prep(const float* __restrict__ X, unsigned short* __restrict__ Xb,
            const float* __restrict__ W0, const float* __restrict__ W1,
            const float* __restrict__ W2, const float* __restrict__ W3,
            unsigned short* __restrict__ Wp,
            const int* __restrict__ ei, int* __restrict__ counts) {
  __shared__ float tile[64][65];
  int b = blockIdx.x, tid = threadIdx.x;

  if (b < PB_PW1) {
    // ---- pack_w1: 4x [3000,512] f32 -> Wp[2048][3072] bf16 (B^T), zero-pad k>=3000
    int k0 = (b % 48) * 64, n0 = (b / 48) * 64;
    int m = n0 >> 9, c0 = n0 & 511;
    const float* W = (m == 0) ? W0 : (m == 1) ? W1 : (m == 2) ? W2 : W3;
    int tx = tid & 63, ty = tid >> 6;
#pragma unroll
    for (int rep = 0; rep < 16; rep++) {
      int i = ty + rep * 4;
      int k = k0 + i;
      tile[i][tx] = (k < K1R) ? W[(size_t)k * 512 + c0 + tx] : 0.f;
    }
    __syncthreads();
#pragma unroll
    for (int rep = 0; rep < 16; rep++) {
      int i = ty + rep * 4;
      Wp[(size_t)(n0 + i) * K1 + k0 + tx] = f2bf(tile[tx][i]);
    }
  } else if (b < PB_CNT) {
    // ---- degree count (self-loops implicit)
    int e = (b - PB_PW1) * 256 + tid;
    if (e < ETOT) {
      int dst = (e < NE) ? ei[NE + e] : (e - NE);
      atomicAdd(&counts[dst], 1);
    }
  } else {
    // ---- convert x f32 -> Xb bf16 [NPAD][3072], zero-pad
    const int CH = K1 / 8;
    int idx = (b - PB_CNT) * 256 + tid;
    if (idx >= NPAD * CH) return;
    int r = idx / CH, c8 = (idx % CH) * 8;
    u16x8 o;
    if (r < NN && c8 < K1R) {
      const float4* p = (const float4*)(X + (size_t)r * K1R + c8);
      float4 a = p[0], bb = p[1];
      o[0]=f2bf(a.x); o[1]=f2bf(a.y); o[2]=f2bf(a.z); o[3]=f2bf(a.w);
      o[4]=f2bf(bb.x); o[5]=f2bf(bb.y); o[6]=f2bf(bb.z); o[7]=f2bf(bb.w);
    } else {
#pragma unroll
      for (int j = 0; j < 8; j++) o[j] = 0;
    }
    *(u16x8*)(Xb + (size_t)r * K1 + c8) = o;
  }
}

// ---------------- pack layer-2 weights (launched AFTER gemm256; B2 aliases Xb) ----------

__global__ __launch_bounds__(256)
void k_pack_w2b(const float* __restrict__ Wl_s, const float* __restrict__ Wr_s,
                const float* __restrict__ Wl_p, const float* __restrict__ Wr_p,
                unsigned short* __restrict__ B2s, unsigned short* __restrict__ B2p) {
  int gidx = blockIdx.x * 256 + threadIdx.x;   // grid 512 -> 131072
  int br = gidx >> 16, idx = gidx & 65535;
  const float* Wl = br ? Wl_p : Wl_s;
  const float* Wr = br ? Wr_p : Wr_s;
  unsigned short* B2 = br ? B2p : B2s;
  int n = idx >> 9, k = idx & 511;
  float v = (n < 64) ? Wl[(size_t)k * 64 + n] : Wr[(size_t)k * 64 + (n - 64)];
  B2[idx] = f2bf(v);
}

// ---------------- CSR scan + scatter ----------------

__global__ void k_scan(const int* __restrict__ counts, int* __restrict__ row_ptr) {
  __shared__ int part[1024];
  int t = threadIdx.x;
  int base = t * 20;
  int loc[20];
  int s = 0;
#pragma unroll
  for (int i = 0; i < 20; i++) {
    int idx = base + i;
    loc[i] = s;
    s += (idx < NN) ? counts[idx] : 0;
  }
  part[t] = s;
  __syncthreads();
  for (int off = 1; off < 1024; off <<= 1) {
    int v = (t >= off) ? part[t - off] : 0;
    __syncthreads();
    part[t] += v;
    __syncthreads();
  }
  int pre = (t > 0) ? part[t - 1] : 0;
#pragma unroll
  for (int i = 0; i < 20; i++) {
    int idx = base + i;
    if (idx <= NN) row_ptr[idx] = pre + loc[i];
  }
}

// scatter using counts as down-counting cursor (no separate fill array):
// pos = row_ptr[d] + (old_count - 1); segment order permuted (softmax order-invariant).
// counts ends at 0 -> deterministic across graph replays (memset re-zeros anyway).
__global__ __launch_bounds__(256)
void k_scatter(const int* __restrict__ ei, const int* __restrict__ row_ptr,
               int* __restrict__ counts, int* __restrict__ csr_src) {
  int e = blockIdx.x * 256 + threadIdx.x;
  if (e >= ETOT) return;
  int s_, d_;
  if (e < NE) { s_ = ei[e]; d_ = ei[NE + e]; } else { s_ = d_ = e - NE; }
  int old = atomicSub(&counts[d_], 1);
  csr_src[row_ptr[d_] + old - 1] = s_;
}

// ---------------- GEMM1: 256x256, role-staggered waves, 1 barrier per K-tile ----------------
// (best measured variant: R6, 298-303 us — FROZEN)

#define NT1 48

#define STAGE_ONE do { \
  if (sctr < 4 * NT1) { \
    int ts_ = sctr >> 2, u_ = sctr & 3, sb_ = ts_ & 1; \
    const unsigned short* gb_; char* lb_; int rb_; \
    if (u_ == 0)      { gb_ = A; rb_ = bmBase + 128; lb_ = lds + (sb_*2+1)*16384; } \
    else if (u_ == 1) { gb_ = B; rb_ = bnBase + 128; lb_ = lds + 65536 + (sb_*2+1)*16384; } \
    else if (u_ == 2) { gb_ = B; rb_ = bnBase;       lb_ = lds + 65536 + (sb_*2+0)*16384; } \
    else              { gb_ = A; rb_ = bmBase;       lb_ = lds + (sb_*2+0)*16384; } \
    const unsigned short* g0_ = gb_ + (size_t)(rb_ + trow) * 3072 + ts_ * 64 + scol; \
    llds16(g0_, lb_ + wid * 1024); \
    llds16(g0_ + (size_t)64 * 3072, lb_ + 8192 + wid * 1024); \
    sctr++; \
  } \
} while (0)

#define RDA(DST, BASE) do { \
  _Pragma("unroll") \
  for (int mi = 0; mi < 2; mi++) { \
    int r_ = rw * 32 + mi * 16 + l15; \
    DST[0][mi] = *(const bf16x8*)((BASE) + r_ * 128 + sw0); \
    DST[1][mi] = *(const bf16x8*)((BASE) + r_ * 128 + sw1); \
  } \
} while (0)

#define RDB(DST, BASE) do { \
  _Pragma("unroll") \
  for (int ni = 0; ni < 4; ni++) { \
    int r_ = cw * 64 + ni * 16 + l15; \
    DST[0][ni] = *(const bf16x8*)((BASE) + r_ * 128 + sw0); \
    DST[1][ni] = *(const bf16x8*)((BASE) + r_ * 128 + sw1); \
  } \
} while (0)

#define MF(MH, NH, AV, BV) do { \
  __builtin_amdgcn_s_setprio(1); \
  _Pragma("unroll") \
  for (int mi = 0; mi < 2; mi++) \
    _Pragma("unroll") \
    for (int ni = 0; ni < 4; ni++) { \
      acc[MH][NH][mi][ni] = __builtin_amdgcn_mfma_f32_16x16x32_bf16(AV[0][mi], BV[0][ni], acc[MH][NH][mi][ni], 0, 0, 0); \
      acc[MH][NH][mi][ni] = __builtin_amdgcn_mfma_f32_16x16x32_bf16(AV[1][mi], BV[1][ni], acc[MH][NH][mi][ni], 0, 0, 0); \
    } \
  __builtin_amdgcn_s_setprio(0); \
} while (0)

__global__ __launch_bounds__(512, 2)
void gemm256(const unsigned short* __restrict__ A, const unsigned short* __restrict__ B,
             unsigned short* __restrict__ C) {
  __shared__ char lds[131072];
  int tid = threadIdx.x, wid = tid >> 6, lane = tid & 63;
  int l15 = lane & 15;
  int rw = wid & 3, cw = wid >> 2;
  int role = (wid >> 2) & 1;
  int bid = blockIdx.x;
  int bn = bid & 7, bm = bid >> 3;
  int bmBase = bm * 256, bnBase = bn * 256;
  int trow = tid >> 3;
  int scol = ((tid & 7) ^ ((tid >> 3) & 7)) * 8;
  int sw0 = (((lane >> 4) + 0) ^ (lane & 7)) * 16;
  int sw1 = (((lane >> 4) + 4) ^ (lane & 7)) * 16;
  f32x4 acc[2][2][2][4] = {};

  int sctr = 0;
  for (int i = 0; i < 4; i++) STAGE_ONE;
  asm volatile("s_waitcnt vmcnt(0)" ::: "memory");
  __builtin_amdgcn_s_barrier();
  asm volatile("" ::: "memory");

  for (int t = 0; t < NT1; t++) {
    int buf = t & 1;
    const char* A0h = lds + (buf * 2 + 0) * 16384;
    const char* A1h = lds + (buf * 2 + 1) * 16384;
    const char* B0h = lds + 65536 + (buf * 2 + 0) * 16384;
    const char* B1h = lds + 65536 + (buf * 2 + 1) * 16384;
    bf16x8 a0[2][2], a1[2][2], b0[2][4], b1[2][4];

    if (role == 0) {
      STAGE_ONE;
      RDA(a0, A0h); RDB(b0, B0h);
      MF(0, 0, a0, b0);
      STAGE_ONE;
      RDA(a1, A1h);
      MF(1, 0, a1, b0);
      STAGE_ONE;
      RDB(b1, B1h);
      MF(1, 1, a1, b1);
      STAGE_ONE;
      MF(0, 1, a0, b1);
    } else {
      STAGE_ONE;
      RDA(a1, A1h); RDB(b1, B1h);
      MF(1, 1, a1, b1);
      STAGE_ONE;
      RDA(a0, A0h);
      MF(0, 1, a0, b1);
      STAGE_ONE;
      RDB(b0, B0h);
      MF(0, 0, a0, b0);
      STAGE_ONE;
      MF(1, 0, a1, b0);
    }
    asm volatile("s_waitcnt vmcnt(0)" ::: "memory");
    __builtin_amdgcn_s_barrier();
    asm volatile("" ::: "memory");
  }

  unsigned short (*sq)[128] = (unsigned short (*)[128])lds;
#pragma unroll
  for (int mh = 0; mh < 2; mh++)
#pragma unroll
    for (int nh = 0; nh < 2; nh++) {
      __syncthreads();
#pragma unroll
      for (int mi = 0; mi < 2; mi++)
#pragma unroll
        for (int ni = 0; ni < 4; ni++)
#pragma unroll
          for (int r = 0; r < 4; r++)
            sq[rw * 32 + mi * 16 + (lane >> 4) * 4 + r][cw * 64 + ni * 16 + l15] =
                f2bf(acc[mh][nh][mi][ni][r]);
      __syncthreads();
#pragma unroll
      for (int it = 0; it < 4; it++) {
        int idx = it * 512 + tid;
        int row = idx >> 4, ch = idx & 15;
        *(u16x8*)(C + (size_t)(bmBase + mh * 128 + row) * NCOL1 + bnBase + nh * 128 + ch * 8) =
            *(const u16x8*)&sq[row][ch * 8];
      }
    }
}

// ---------------- layer-2 GEMM (128-tile m97 structure), both branches, K=512 ----------------

__global__ __launch_bounds__(256)
void gemm_l2(const unsigned short* __restrict__ As, const unsigned short* __restrict__ Bs,
             float* __restrict__ Cs,
             const unsigned short* __restrict__ Ap, const unsigned short* __restrict__ Bp,
             float* __restrict__ Cp) {
  const int K = LDA2, lda = LDA2, ldb = LDA2, ldc = 128, mreal = NN;
  const unsigned short* A = blockIdx.y ? Ap : As;
  const unsigned short* B = blockIdx.y ? Bp : Bs;
  float* C = blockIdx.y ? Cp : Cs;
  __shared__ char smem_raw[16384];
  unsigned short* sA = (unsigned short*)smem_raw;
  unsigned short* sB = sA + 128 * 32;
  int bm = blockIdx.x;
  int tid = threadIdx.x, wid = tid >> 6, lane = tid & 63;
  int wr = wid >> 1, wc = wid & 1;
  f32x4 acc[4][4] = {};

  int ar = 32 * wid + (lane >> 2);
  int acol = (lane & 3) * 8;
  const unsigned short* Ag = A + (size_t)(bm * 128 + ar) * lda + acol;
  const unsigned short* Bg = B + (size_t)ar * ldb + acol;
  unsigned short* la0 = sA + (wid * 2) * 512;
  unsigned short* lb0 = sB + (wid * 2) * 512;
  int frow = lane & 15, koff = (lane >> 4) * 8;

  for (int kt = 0; kt < K; kt += 32) {
    llds16(Ag + kt, la0);
    llds16(Ag + kt + (size_t)16 * lda, la0 + 512);
    llds16(Bg + kt, lb0);
    llds16(Bg + kt + (size_t)16 * ldb, lb0 + 512);
    __syncthreads();
    bf16x8 af[4], bfr[4];
#pragma unroll
    for (int mi = 0; mi < 4; mi++)
      af[mi] = *(const bf16x8*)(sA + (wr * 64 + mi * 16 + frow) * 32 + koff);
#pragma unroll
    for (int ni = 0; ni < 4; ni++)
      bfr[ni] = *(const bf16x8*)(sB + (wc * 64 + ni * 16 + frow) * 32 + koff);
#pragma unroll
    for (int mi = 0; mi < 4; mi++)
#pragma unroll
      for (int ni = 0; ni < 4; ni++)
        acc[mi][ni] = __builtin_amdgcn_mfma_f32_16x16x32_bf16(af[mi], bfr[ni], acc[mi][ni], 0, 0, 0);
    __syncthreads();
  }

#pragma unroll
  for (int mi = 0; mi < 4; mi++) {
    int grow0 = bm * 128 + wr * 64 + mi * 16 + (lane >> 4) * 4;
#pragma unroll
    for (int ni = 0; ni < 4; ni++) {
      int gcol = wc * 64 + ni * 16 + (lane & 15);
#pragma unroll
      for (int r = 0; r < 4; r++) {
        int grow = grow0 + r;
        if (grow < mreal) C[(size_t)grow * ldc + gcol] = acc[mi][ni][r];
      }
    }
  }
}

// ---------------- layer-1 edge softmax+aggregate: BOTH branches per wave + prefetch -------

__global__ __launch_bounds__(256)
void edge_agg1(const unsigned short* __restrict__ XL1,
               const int* __restrict__ row_ptr, const int* __restrict__ csr_src,
               const float* __restrict__ att_s, const float* __restrict__ att_p,
               const float* __restrict__ b_s, const float* __restrict__ b_p,
               unsigned short* __restrict__ A2s, unsigned short* __restrict__ A2p) {
  int n = (blockIdx.x * 256 + threadIdx.x) >> 6;
  if (n >= NN) return;
  int lane = threadIdx.x & 63;
  int cb = lane * 8;
  float xs[8], xp[8], as_[8], ap_[8], aggs[8], aggp[8];
  {
    bf16x8 xsv = *(const bf16x8*)(XL1 + (size_t)n * NCOL1 + 512 + cb);
    bf16x8 xpv = *(const bf16x8*)(XL1 + (size_t)n * NCOL1 + 1536 + cb);
    float4 a0 = *(const float4*)(att_s + cb), a1 = *(const float4*)(att_s + cb + 4);
    float4 a2 = *(const float4*)(att_p + cb), a3 = *(const float4*)(att_p + cb + 4);
    as_[0]=a0.x; as_[1]=a0.y; as_[2]=a0.z; as_[3]=a0.w; as_[4]=a1.x; as_[5]=a1.y; as_[6]=a1.z; as_[7]=a1.w;
    ap_[0]=a2.x; ap_[1]=a2.y; ap_[2]=a2.z; ap_[3]=a2.w; ap_[4]=a3.x; ap_[5]=a3.y; ap_[6]=a3.z; ap_[7]=a3.w;
#pragma unroll
    for (int j = 0; j < 8; j++) { xs[j] = (float)xsv[j]; xp[j] = (float)xpv[j]; aggs[j] = 0.f; aggp[j] = 0.f; }
  }
  float Ms = -1e30f, Ss = 0.f, Mp = -1e30f, Sp = 0.f;
  int p0 = row_ptr[n], pe = row_ptr[n + 1];
  int src = csr_src[p0];
  bf16x8 ms = *(const bf16x8*)(XL1 + (size_t)src * NCOL1 + cb);
  bf16x8 mp = *(const bf16x8*)(XL1 + (size_t)src * NCOL1 + 1024 + cb);
  for (int p = p0; p < pe; ++p) {
    bf16x8 cs = ms, cp = mp;
    if (p + 1 < pe) {
      int s2 = csr_src[p + 1];
      ms = *(const bf16x8*)(XL1 + (size_t)s2 * NCOL1 + cb);
      mp = *(const bf16x8*)(XL1 + (size_t)s2 * NCOL1 + 1024 + cb);
    }
    float mjs[8], mjp[8], ps_ = 0.f, pp_ = 0.f;
#pragma unroll
    for (int j = 0; j < 8; j++) {
      mjs[j] = (float)cs[j];
      float t = mjs[j] + xs[j];
      t = (t > 0.f) ? t : 0.2f * t;
      ps_ = fmaf(as_[j], t, ps_);
      mjp[j] = (float)cp[j];
      float u = mjp[j] + xp[j];
      u = (u > 0.f) ? u : 0.2f * u;
      pp_ = fmaf(ap_[j], u, pp_);
    }
#pragma unroll
    for (int w = 1; w < 16; w <<= 1) { ps_ += __shfl_xor(ps_, w); pp_ += __shfl_xor(pp_, w); }
    float nms = fmaxf(Ms, ps_);
    float fs = __expf(Ms - nms), ws_ = __expf(ps_ - nms);
    Ss = Ss * fs + ws_;
    float nmp = fmaxf(Mp, pp_);
    float fp = __expf(Mp - nmp), wp_ = __expf(pp_ - nmp);
    Sp = Sp * fp + wp_;
#pragma unroll
    for (int j = 0; j < 8; j++) {
      aggs[j] = aggs[j] * fs + ws_ * mjs[j];
      aggp[j] = aggp[j] * fp + wp_ * mjp[j];
    }
    Ms = nms; Mp = nmp;
  }
  float invs = 1.f / Ss, invp = 1.f / Sp;
  u16x8 hs, hp;
#pragma unroll
  for (int j = 0; j < 8; j++) {
    float v = fmaxf(aggs[j] * invs + b_s[cb + j], 0.f);
    hs[j] = f2bf(v);
    float u = aggp[j] * invp + b_p[cb + j];
    hp[j] = f2bf(u);
  }
  *(u16x8*)(A2s + (size_t)n * LDA2 + cb) = hs;
  *(u16x8*)(A2p + (size_t)n * LDA2 + cb) = hp;
}

// ---------------- layer-2 edge softmax+aggregate+epilogue: BOTH branches per wave + prefetch ----

__global__ __launch_bounds__(256)
void edge_agg2(const float* __restrict__ C2s, const float* __restrict__ C2p,
               const int* __restrict__ row_ptr, const int* __restrict__ csr_src,
               const float* __restrict__ att_s, const float* __restrict__ att_p,
               const float* __restrict__ b_s, const float* __restrict__ b_p,
               float* __restrict__ out) {
  int n = (blockIdx.x * 256 + threadIdx.x) >> 6;
  if (n >= NN) return;
  int lane = threadIdx.x & 63;
  float xrs = C2s[(size_t)n * 128 + 64 + lane];
  float xrp = C2p[(size_t)n * 128 + 64 + lane];
  float ats = att_s[lane], atp = att_p[lane];
  float Ms = -1e30f, Ss = 0.f, ags = 0.f;
  float Mp = -1e30f, Sp = 0.f, agp = 0.f;
  int p0 = row_ptr[n], pe = row_ptr[n + 1];
  int src = csr_src[p0];
  float ms = C2s[(size_t)src * 128 + lane];
  float mp = C2p[(size_t)src * 128 + lane];
  for (int p = p0; p < pe; ++p) {
    float cs = ms, cp = mp;
    if (p + 1 < pe) {
      int s2 = csr_src[p + 1];
      ms = C2s[(size_t)s2 * 128 + lane];
      mp = C2p[(size_t)s2 * 128 + lane];
    }
    float t = cs + xrs; t = (t > 0.f) ? t : 0.2f * t;
    float u = cp + xrp; u = (u > 0.f) ? u : 0.2f * u;
    float ps_ = ats * t, pp_ = atp * u;
#pragma unroll
    for (int w = 1; w < 64; w <<= 1) { ps_ += __shfl_xor(ps_, w); pp_ += __shfl_xor(pp_, w); }
    float nms = fmaxf(Ms, ps_);
    float fs = __expf(Ms - nms), ws_ = __expf(ps_ - nms);
    Ss = Ss * fs + ws_; ags = ags * fs + ws_ * cs; Ms = nms;
    float nmp = fmaxf(Mp, pp_);
    float fp = __expf(Mp - nmp), wp_ = __expf(pp_ - nmp);
    Sp = Sp * fp + wp_; agp = agp * fp + wp_ * cp; Mp = nmp;
  }
  float vs = ags / Ss + b_s[lane];
  float vp = agp / Sp + b_p[lane];
  if (lane < 32) {
    out[(size_t)n * 64 + lane] = vs;
    out[(size_t)n * 64 + 32 + lane] = vp;
  } else {
    float sps = fmaxf(vs, 0.f) + log1pf(__expf(-fabsf(vs))) + 1e-6f;
    float spp = fmaxf(vp, 0.f) + log1pf(__expf(-fabsf(vp))) + 1e-6f;
    out[(size_t)MU_SZ + n * 64 + (lane - 32)] = sps;
    out[(size_t)MU_SZ + n * 64 + 32 + (lane - 32)] = spp;
  }
}

// ---------------- host ----------------

extern "C" void kernel_launch(void* const* d_in, const int* in_sizes, int n_in,
                              void* d_out, int out_size, void* d_ws, size_t ws_size,
                              hipStream_t stream) {
  const float* x      = (const float*)d_in[0];
  const int*   ei     = (const int*)d_in[1];
  const float* Wl_s1  = (const float*)d_in[2];
  const float* Wr_s1  = (const float*)d_in[3];
  const float* att_s1 = (const float*)d_in[4];
  const float* b_s1   = (const float*)d_in[5];
  const float* Wl_s2  = (const float*)d_in[6];
  const float* Wr_s2  = (const float*)d_in[7];
  const float* att_s2 = (const float*)d_in[8];
  const float* b_s2   = (const float*)d_in[9];
  const float* Wl_p1  = (const float*)d_in[10];
  const float* Wr_p1  = (const float*)d_in[11];
  const float* att_p1 = (const float*)d_in[12];
  const float* b_p1   = (const float*)d_in[13];
  const float* Wl_p2  = (const float*)d_in[14];
  const float* Wr_p2  = (const float*)d_in[15];
  const float* att_p2 = (const float*)d_in[16];
  const float* b_p2   = (const float*)d_in[17];

  char* ws = (char*)d_ws;
  unsigned short* Xb   = (unsigned short*)(ws + 0);           // 20224*3072*2 = 124,256,256
  unsigned short* A2s  = (unsigned short*)(ws + 0);           // 20096*512*2 = 20,578,304 (after Xb dead)
  unsigned short* A2p  = (unsigned short*)(ws + 20578304);    // 20,578,304
  float*          C2s  = (float*)(ws + 41156608);             // 10,240,000
  float*          C2p  = (float*)(ws + 51396608);             // 10,240,000
  unsigned short* B2s  = (unsigned short*)(ws + 61636608);    // 131,072 (aliases Xb; written post-gemm256)
  unsigned short* B2p  = (unsigned short*)(ws + 61767680);    // 131,072
  unsigned short* Wp   = (unsigned short*)(ws + 124256256);   // 12,582,912
  unsigned short* XL1  = (unsigned short*)(ws + 136839168);   // 20224*2048*2 = 82,837,504
  int* counts  = (int*)(ws + 219676672);                      // 80,000
  int* row_ptr = (int*)(ws + 219836672);                      // 80,004
  int* csr_src = (int*)(ws + 219916688);                      // 1,360,000

  hipMemsetAsync(counts, 0, NN * sizeof(int), stream);

  k_prep<<<PB_CVT, 256, 0, stream>>>(x, Xb, Wl_s1, Wr_s1, Wl_p1, Wr_p1, Wp, ei, counts);
  k_scan<<<1, 1024, 0, stream>>>(counts, row_ptr);
  k_scatter<<<(ETOT + 255) / 256, 256, 0, stream>>>(ei, row_ptr, counts, csr_src);

  // XL1[n, 0:512|512:1024|1024:1536|1536:2048] = x@{Wl_s1|Wr_s1|Wl_p1|Wr_p1}, bf16
  gemm256<<<632, 512, 0, stream>>>(Xb, Wp, XL1);

  k_pack_w2b<<<512, 256, 0, stream>>>(Wl_s2, Wr_s2, Wl_p2, Wr_p2, B2s, B2p);

  edge_agg1<<<5000, 256, 0, stream>>>(XL1, row_ptr, csr_src, att_s1, att_p1, b_s1, b_p1, A2s, A2p);

  gemm_l2<<<dim3(157, 2), 256, 0, stream>>>(A2s, B2s, C2s, A2p, B2p, C2p);

  edge_agg2<<<5000, 256, 0, stream>>>(C2s, C2p, row_ptr, csr_src, att_s2, att_p2, b_s2, b_p2, (float*)d_out);
}